// Round 4
// baseline (268.983 us; speedup 1.0000x reference)
//
#include <hip/hip_runtime.h>
#include <hip/hip_bf16.h>
#include <math.h>

constexpr int F   = 1433;
constexpr int NB  = 64;
constexpr int KN  = 8;
constexpr int BF  = NB * F;            // 91712
constexpr float EPS = 1e-5f;

constexpr int SF  = 16;                // splits for D / y1 phases: 64*16 = 1024
constexpr int CH  = 90;                // 16*90 = 1440 >= F
constexpr int AbS = 1440;              // Ab row stride (zero-padded)
constexpr int SK  = 15;                // gemm splits: 15*96 = 1440
constexpr int FT  = 12;                // A f-tile
constexpr int NFT = 120;               // 120*12 = 1440 >= F
constexpr int NAF = NFT * 3;           // fused A units (512 thr: 3 gx) = 360
constexpr int NAL = NFT * 6;           // legacy A units (256 thr: 6 gx) = 720
constexpr int NST = 256;               // stats units
constexpr int NFP = 23;                // gemm f-pairs (23*64 = 1472 >= F)
constexpr int NGU = NFP * SK;          // gemm units = 345
constexpr int NGRID = 1024;            // fused grid: 4 blk/CU * 256 CU

// Workspace (float offsets); ws is 256 MiB
constexpr int O_YS  = 0;                       // [BF]
constexpr int O_DP  = O_YS + BF;               // [SF*BF] D partials
constexpr int O_Y1P = O_DP + SF * BF;          // [SF*BF] y1 partials
constexpr int O_P   = O_Y1P + SF * BF;         // [4*BF]  float4 (x,ys,w,q)
constexpr int O_Y1  = O_P + 4 * BF;            // [BF]
constexpr int O_Y2  = O_Y1 + BF;               // [2*BF]
constexpr int O_G2P = O_Y2 + 2 * BF;           // [SK*128*F] gemm partials
constexpr int O_AB  = O_G2P + SK * 128 * F;    // [F*AbS halfs] bf16 A
constexpr int O_ST  = O_AB + (F * AbS) / 2;    // [64] stats (memset to 0)
constexpr int O_BAR = O_ST + 64;               // [258] barrier words

// Device-scope (sc1) write-through store: value visible at the L3 coherence
// point once vmcnt drains — no buffer_wbl2 / buffer_inv needed at barriers.
__device__ __forceinline__ void devst(float* p, float v) {
  __hip_atomic_store(p, v, __ATOMIC_RELAXED, __HIP_MEMORY_SCOPE_AGENT);
}
__device__ __forceinline__ void devst16(ushort* p, ushort v) {
  __hip_atomic_store(p, v, __ATOMIC_RELAXED, __HIP_MEMORY_SCOPE_AGENT);
}
__device__ __forceinline__ void devst4(float4* p, float4 v) {
  union { float2 f; unsigned long long u; } lo, hi;
  lo.f = make_float2(v.x, v.y);
  hi.f = make_float2(v.z, v.w);
  unsigned long long* q = (unsigned long long*)p;
  __hip_atomic_store(q + 0, lo.u, __ATOMIC_RELAXED, __HIP_MEMORY_SCOPE_AGENT);
  __hip_atomic_store(q + 1, hi.u, __ATOMIC_RELAXED, __HIP_MEMORY_SCOPE_AGENT);
}
__device__ __forceinline__ float devld(const float* p) {
  return __hip_atomic_load(p, __ATOMIC_RELAXED, __HIP_MEMORY_SCOPE_AGENT);
}

// ---------------------------------------------------------------------------
// Cache-op-free grid barrier (r2-verified): relaxed atomics only; data
// coherence via sc1 write-through + __syncthreads vmcnt drain. gridDim%8==0.
// ---------------------------------------------------------------------------
__device__ __forceinline__ void grid_barrier(unsigned* bar, unsigned phase) {
  __syncthreads();                     // drains vmcnt(0): block's sc1 stores at L3
  if (threadIdx.x == 0) {
    const unsigned ngrp = gridDim.x >> 3;
    const unsigned grp = (unsigned)blockIdx.x & 7u;
    unsigned old = __hip_atomic_fetch_add(&bar[grp * 32], 1u,
                                          __ATOMIC_RELAXED, __HIP_MEMORY_SCOPE_AGENT);
    if (old == phase * ngrp - 1u) {
      unsigned m = __hip_atomic_fetch_add(&bar[256], 1u,
                                          __ATOMIC_RELAXED, __HIP_MEMORY_SCOPE_AGENT);
      if (m == phase * 8u - 1u)
        __hip_atomic_store(&bar[257], phase, __ATOMIC_RELAXED, __HIP_MEMORY_SCOPE_AGENT);
    }
    while (__hip_atomic_load(&bar[257], __ATOMIC_RELAXED, __HIP_MEMORY_SCOPE_AGENT) < phase)
      __builtin_amdgcn_s_sleep(32);
  }
  __syncthreads();
}

// ---------------------------------------------------------------------------
// Fused persistent pipeline, 512-thread blocks (8 waves), r2 phase geometry:
// D(+ys) -> y1/P -> A+stats1 -> gemm -> stats2 -> out.  1024 blocks, every
// phase has <= 1024 units so each block runs <= 1 unit (no stragglers).
// ---------------------------------------------------------------------------
__global__ __launch_bounds__(512, 8) void k_fused(
    const float* __restrict__ x, const float* __restrict__ nbr,
    const float* __restrict__ W1, const float* __restrict__ g1,
    const float* __restrict__ be1, const float* __restrict__ W2,
    const float* __restrict__ b2, const float* __restrict__ g2,
    const float* __restrict__ be2, const float* __restrict__ Wc,
    const float* __restrict__ bc, float* __restrict__ out,
    float* __restrict__ ws) {
  float*  ys  = ws + O_YS;
  float*  DP  = ws + O_DP;
  float*  Y1P = ws + O_Y1P;
  float4* P   = (float4*)(ws + O_P);
  float*  y1  = ws + O_Y1;
  float*  y2  = ws + O_Y2;
  float*  G2P = ws + O_G2P;
  ushort* Ab  = (ushort*)(ws + O_AB);
  const ushort* Abu = (const ushort*)(ws + O_AB);
  float*  st  = ws + O_ST;
  unsigned* bar = (unsigned*)(ws + O_BAR);

  __shared__ __align__(16) char smem[26112];   // union; gemm needs 2*Al+Hl
  const int tid = threadIdx.x;
  const int gsz = (int)gridDim.x;

  // ---------------- phase 1: D partials; s==0 stores ys (1024 units) -------
  {
    float2* xyc = (float2*)smem;
    for (int w = blockIdx.x; w < NB * SF; w += gsz) {
      const int b = w & 63, s = w >> 6;
      __syncthreads();                 // guard xyc reuse across w iterations
      const int cs = s * CH, cn = min(CH, F - cs);
      if (tid < cn) {
        const float* p = nbr + (size_t)b * KN * F + cs + tid;
        float a = 0.f;
#pragma unroll
        for (int k = 0; k < KN; ++k) a += p[k * F];
        xyc[tid] = make_float2(x[b * F + cs + tid], a);
      }
      __syncthreads();
      float gx[3], gy[3], acc[3] = {};
#pragma unroll
      for (int j = 0; j < 3; ++j) {
        int g = tid + 512 * j;
        int gc = min(g, F - 1);
        const float* p = nbr + (size_t)b * KN * F + gc;
        float a = 0.f;
#pragma unroll
        for (int k = 0; k < KN; ++k) a += p[k * F];
        gx[j] = (g < F) ? x[b * F + gc] : 0.f;
        gy[j] = (g < F) ? a : 0.f;
      }
      if (s == 0) {
#pragma unroll
        for (int j = 0; j < 3; ++j) {
          int g = tid + 512 * j;
          if (g < F) devst(&ys[b * F + g], gy[j]);
        }
      }
#pragma unroll 6
      for (int i = 0; i < cn; ++i) {
        float2 p = xyc[i];   // LDS broadcast, conflict-free
#pragma unroll
        for (int j = 0; j < 3; ++j)
          acc[j] += __builtin_amdgcn_sqrtf(fmaf(gy[j], p.x, gx[j] * p.y));
      }
#pragma unroll
      for (int j = 0; j < 3; ++j) {
        int g = tid + 512 * j;
        if (g < F) devst(&DP[(size_t)s * BF + b * F + g], acc[j]);
      }
    }
  }
  grid_barrier(bar, 1u);

  // ---------------- phase 2: y1 partials; D-reduce -> P (1024 units) -------
  {
    float4* pl = (float4*)smem;
    for (int w = blockIdx.x; w < NB * SF; w += gsz) {
      const int b = w & 63, s = w >> 6;
      __syncthreads();                 // guard pl reuse
      const int cs = s * CH, cn = min(CH, F - cs);
      if (tid < cn) {
        int g = cs + tid;
        float d = 0.f;
#pragma unroll
        for (int t = 0; t < SF; ++t) d += DP[(size_t)t * BF + b * F + g];
        float inv = (d > 0.f) ? 1.f / d : 0.f;
        float xv = x[b * F + g], yv = ys[b * F + g];
        float4 pv = make_float4(xv, yv, xv * inv, inv);
        pl[tid] = pv;
        devst4(&P[b * F + g], pv);
      }
      __syncthreads();
      float fx[3], fys[3], acc[3] = {};
#pragma unroll
      for (int j = 0; j < 3; ++j) {
        int f = tid + 512 * j;
        int fc = min(f, F - 1);
        fx[j]  = (f < F) ? x[b * F + fc] : 0.f;
        fys[j] = (f < F) ? ys[b * F + fc] : 0.f;
      }
#pragma unroll 6
      for (int i = 0; i < cn; ++i) {
        float4 p = pl[i];   // broadcast
#pragma unroll
        for (int j = 0; j < 3; ++j)
          acc[j] = fmaf(__builtin_amdgcn_sqrtf(fmaf(fx[j], p.y, fys[j] * p.x)), p.z, acc[j]);
      }
#pragma unroll
      for (int j = 0; j < 3; ++j) {
        int f = tid + 512 * j;
        if (f < F) devst(&Y1P[(size_t)s * BF + b * F + f], acc[j]);
      }
    }
  }
  grid_barrier(bar, 2u);

  // ---------------- phase 3: A-build (360 units) + stats1 (256 units) ------
  {
    for (int w = blockIdx.x; w < NAF + NST; w += gsz) {
      __syncthreads();                 // guard smem reuse across w iterations
      if (w < NAF) {
        float2 (*fxy)[NB] = (float2(*)[NB])smem;   // FT*NB*8 = 6 KB
        const int gxc = w % 3, fyt = w / 3;
        const int fbase = fyt * FT;
#pragma unroll
        for (int r = 0; r < 2; ++r) {    // FT*NB = 768
          int i = tid + 512 * r;
          if (i < FT * NB) {
            int j = i >> 6, bb = i & 63;
            int f = fbase + j;
            float vx = 0.f, vy = 0.f;
            if (f < F) { vx = x[bb * F + f]; vy = ys[bb * F + f]; }
            fxy[j][bb] = make_float2(vx, vy);
          }
        }
        __syncthreads();
        const int g = gxc * 512 + tid;
        if (g < F) {
          float acc[FT] = {};
          float4 cur[4], nxt[4];
#pragma unroll
          for (int t = 0; t < 4; ++t) cur[t] = P[t * F + g];
          for (int bb = 0; bb < NB; bb += 4) {
            if (bb + 4 < NB) {
#pragma unroll
              for (int t = 0; t < 4; ++t) nxt[t] = P[(bb + 4 + t) * F + g];
            }
#pragma unroll
            for (int t = 0; t < 4; ++t) {
              float4 pc = cur[t];
#pragma unroll
              for (int j = 0; j < FT; ++j) {
                float2 wv = fxy[j][bb + t];   // broadcast
                acc[j] = fmaf(__builtin_amdgcn_sqrtf(fmaf(wv.x, pc.y, pc.x * wv.y)), pc.w, acc[j]);
              }
            }
#pragma unroll
            for (int t = 0; t < 4; ++t) cur[t] = nxt[t];
          }
#pragma unroll
          for (int j = 0; j < FT; ++j) {
            int f = fbase + j;
            if (f < F) {
              __hip_bfloat16 hv = __float2bfloat16(acc[j]);
              devst16(&Ab[(size_t)f * AbS + g], *reinterpret_cast<ushort*>(&hv));
            }
          }
        } else if (g < AbS) {            // zero pad cols [F, AbS)
#pragma unroll
          for (int j = 0; j < FT; ++j) {
            int f = fbase + j;
            if (f < F) devst16(&Ab[(size_t)f * AbS + g], (ushort)0);
          }
        }
      } else {
        const int sid = w - NAF;
        float sv = 0.f, sq = 0.f;
        for (int i = sid * 512 + tid; i < BF; i += NST * 512) {
          float v = x[i];
#pragma unroll
          for (int t = 0; t < SF; ++t) v += Y1P[(size_t)t * BF + i];
          devst(&y1[i], v);
          sv += v; sq += v * v;
        }
#pragma unroll
        for (int o = 32; o; o >>= 1) {
          sv += __shfl_down(sv, o, 64);
          sq += __shfl_down(sq, o, 64);
        }
        float* ls = (float*)smem;      // [8] + [8]
        float* lq = ls + 8;
        int wave = tid >> 6, lane = tid & 63;
        if (lane == 0) { ls[wave] = sv; lq[wave] = sq; }
        __syncthreads();
        if (tid == 0) {
          float a = 0.f, bsum = 0.f;
#pragma unroll
          for (int q = 0; q < 8; ++q) { a += ls[q]; bsum += lq[q]; }
          atomicAdd(&st[0], a);
          atomicAdd(&st[1], bsum);
        }
      }
    }
  }
  grid_barrier(bar, 3u);

  // ---------------- phase 4: gemm (345 units, two 256-thr halves) ----------
  {
    const float mu  = st[0] / (float)BF;
    const float var = st[1] / (float)BF - mu * mu;
    const float wa = W1[0], wb = W1[1];
    const float k0 = wa * g1[0] / sqrtf(wa * wa * var + EPS);
    const float k1 = wb * g1[1] / sqrtf(wb * wb * var + EPS);
    const float c0 = -k0 * mu + be1[0];
    const float c1 = -k1 * mu + be1[1];

    const int half = tid >> 8, t = tid & 255;
    float* Al = (float*)smem + half * (32 * 36);   // 2 * 4.6 KB
    float* Hl = (float*)smem + 2 * (32 * 36);      // 32*132 floats = 16.9 KB
    const int ffs = t >> 3, g4s = (t & 7) * 4;
    const int hb = t & 7, hg = t >> 3;
    const int fsub = (t & 7) * 4, msub = (t >> 3) * 4;

    for (int w = blockIdx.x; w < NGU; w += gsz) {
      const int fp = w % NFP, sk = w / NFP;
      const int f0 = fp * 64 + half * 32;
      const int gs = sk * 96;
      __syncthreads();                 // guard Al/Hl reuse across w iterations

      uint2 pa; float pyv[8];
      auto loadRegs = [&](int gb) {
        const int f = f0 + ffs;
        pa = make_uint2(0u, 0u);
        if (f < F) pa = *(const uint2*)&Abu[(size_t)f * AbS + gb + g4s];
        const int gl = min(gb + hg, F - 1);   // pad cols of A are 0
#pragma unroll
        for (int r = 0; r < 8; ++r) pyv[r] = y1[(hb + 8 * r) * F + gl];
      };
      auto storeLDS = [&]() {
        Al[(g4s + 0) * 36 + ffs] = __uint_as_float(pa.x << 16);
        Al[(g4s + 1) * 36 + ffs] = __uint_as_float(pa.x & 0xffff0000u);
        Al[(g4s + 2) * 36 + ffs] = __uint_as_float(pa.y << 16);
        Al[(g4s + 3) * 36 + ffs] = __uint_as_float(pa.y & 0xffff0000u);
        // both halves write identical H values to the shared Hl — benign.
#pragma unroll
        for (int r = 0; r < 8; ++r) {
          const int bb = hb + 8 * r;
          const float v = pyv[r];
          float h0 = fmaf(k0, v, c0); h0 = h0 / (1.f + fabsf(h0));
          float h1 = fmaf(k1, v, c1); h1 = h1 / (1.f + fabsf(h1));
          *(float2*)&Hl[hg * 132 + 2 * bb] = make_float2(h0, h1);
        }
      };

      float acc[4][4] = {};
      loadRegs(gs);
      for (int c = 0; c < 3; ++c) {
        if (c) __syncthreads();
        storeLDS();
        __syncthreads();
        if (c < 2) loadRegs(gs + (c + 1) * 32);
#pragma unroll 4
        for (int gi = 0; gi < 32; ++gi) {
          float4 a4 = *(const float4*)&Al[gi * 36 + fsub];
          float4 h4 = *(const float4*)&Hl[gi * 132 + msub];
          float av[4] = {a4.x, a4.y, a4.z, a4.w};
          float hv[4] = {h4.x, h4.y, h4.z, h4.w};
#pragma unroll
          for (int i = 0; i < 4; ++i)
#pragma unroll
            for (int j = 0; j < 4; ++j)
              acc[i][j] = fmaf(av[i], hv[j], acc[i][j]);
        }
      }
      float* dst = G2P + (size_t)sk * 128 * F;
#pragma unroll
      for (int i = 0; i < 4; ++i) {
        int f = f0 + fsub + i;
        if (f < F) {
#pragma unroll
          for (int j = 0; j < 4; ++j)
            devst(&dst[(msub + j) * F + f], acc[i][j]);
        }
      }
    }
  }
  grid_barrier(bar, 4u);

  // ---------------- phase 5: reduce partials + 64*H diag -> y2, moments ----
  {
    const float mu  = st[0] / (float)BF;
    const float var = st[1] / (float)BF - mu * mu;
    const float wa = W1[0], wb = W1[1];
    const float k0 = wa * g1[0] / sqrtf(wa * wa * var + EPS);
    const float k1 = wb * g1[1] / sqrtf(wb * wb * var + EPS);
    const float c0 = -k0 * mu + be1[0];
    const float c1 = -k1 * mu + be1[1];

    float su = 0.f, sv = 0.f, suu = 0.f, svv = 0.f, suv = 0.f;
    for (int i = blockIdx.x * 512 + tid; i < BF; i += gsz * 512) {
      int b = i / F, f = i - b * F;
      float wv = y1[i];
      float h0 = fmaf(k0, wv, c0); h0 = h0 / (1.f + fabsf(h0));
      float h1 = fmaf(k1, wv, c1); h1 = h1 / (1.f + fabsf(h1));
      int iu = (2 * b) * F + f, iv = iu + F;
      float u = 64.f * h0, v = 64.f * h1;
#pragma unroll
      for (int t = 0; t < SK; ++t) {
        u += G2P[(size_t)t * 128 * F + iu];
        v += G2P[(size_t)t * 128 * F + iv];
      }
      devst(&y2[iu], u); devst(&y2[iv], v);
      su += u; sv += v; suu += u * u; svv += v * v; suv += u * v;
    }
#pragma unroll
    for (int o = 32; o; o >>= 1) {
      su  += __shfl_down(su, o, 64);
      sv  += __shfl_down(sv, o, 64);
      suu += __shfl_down(suu, o, 64);
      svv += __shfl_down(svv, o, 64);
      suv += __shfl_down(suv, o, 64);
    }
    float (*red)[8] = (float(*)[8])smem;   // [5][8]
    int wave = tid >> 6, lane = tid & 63;
    if (lane == 0) {
      red[0][wave] = su; red[1][wave] = sv; red[2][wave] = suu;
      red[3][wave] = svv; red[4][wave] = suv;
    }
    __syncthreads();
    if (tid == 0) {
#pragma unroll
      for (int m = 0; m < 5; ++m) {
        float a = 0.f;
#pragma unroll
        for (int q = 0; q < 8; ++q) a += red[m][q];
        atomicAdd(&st[2 + m], a);
      }
    }
  }
  grid_barrier(bar, 5u);

  // ---------------- phase 6: final classifier (64 units, direct store) -----
  {
    float n = (float)BF;
    // st[2..6] share a cache line with st[0..1] (plain-loaded in phases 4/5)
    // — sc1 loads dodge the stale-L2-line hazard.
    float Eu = devld(&st[2]) / n, Ev = devld(&st[3]) / n;
    float Euu = devld(&st[4]) / n, Evv = devld(&st[5]) / n, Euv = devld(&st[6]) / n;
    float cA[2], cB[2], cC[2];
#pragma unroll
    for (int o = 0; o < 2; ++o) {
      float w0 = W2[o * 2 + 0], w1 = W2[o * 2 + 1];
      float mean = w0 * Eu + w1 * Ev + b2[o];
      float Eh2 = w0 * w0 * Euu + 2.f * w0 * w1 * Euv + w1 * w1 * Evv +
                  2.f * b2[o] * (w0 * Eu + w1 * Ev) + b2[o] * b2[o];
      float vr = Eh2 - mean * mean;
      float inv = g2[o] / sqrtf(vr + EPS);
      cA[o] = w0 * inv;
      cB[o] = w1 * inv;
      cC[o] = (b2[o] - mean) * inv + be2[o];
    }
    float (*red)[8] = (float(*)[8])smem;   // [7][8]
    for (int w = blockIdx.x; w < NB; w += gsz) {
      const int b = w;
      float acc[7] = {};
      for (int f = tid; f < F; f += 512) {
        float u = y2[(2 * b) * F + f], v = y2[(2 * b + 1) * F + f];
        float h0 = fmaf(cA[0], u, fmaf(cB[0], v, cC[0]));
        h0 = h0 / (1.f + fabsf(h0));
        float h1 = fmaf(cA[1], u, fmaf(cB[1], v, cC[1]));
        h1 = h1 / (1.f + fabsf(h1));
#pragma unroll
        for (int o = 0; o < 7; ++o)
          acc[o] = fmaf(Wc[o * (2 * F) + f], h0,
                        fmaf(Wc[o * (2 * F) + F + f], h1, acc[o]));
      }
#pragma unroll
      for (int o = 0; o < 7; ++o) {
#pragma unroll
        for (int s2 = 32; s2; s2 >>= 1) acc[o] += __shfl_down(acc[o], s2, 64);
      }
      __syncthreads();
      int wave = tid >> 6, lane = tid & 63;
      if (lane == 0) {
#pragma unroll
        for (int o = 0; o < 7; ++o) red[o][wave] = acc[o];
      }
      __syncthreads();
      if (tid < 7) {
        float a = bc[tid];
#pragma unroll
        for (int q = 0; q < 8; ++q) a += red[tid][q];
        out[b * 7 + tid] = a;
      }
    }
  }
}

// ===========================================================================
// Legacy multi-kernel fallback (r2's 205-us baseline path) — used only if
// the fused kernel cannot be co-resident at >=256 blocks.
// ===========================================================================
__global__ __launch_bounds__(256) void k_D(const float* __restrict__ x,
                                           const float* __restrict__ nbr,
                                           float* __restrict__ DP,
                                           float* __restrict__ ys_out,
                                           float* __restrict__ st) {
  const int b = blockIdx.x, s = blockIdx.y;
  if (b == 0 && s == 0 && threadIdx.x < 64) st[threadIdx.x] = 0.f;
  __shared__ __align__(8) float2 xyc[CH];
  const int cs = s * CH, cn = min(CH, F - cs);
  for (int i = threadIdx.x; i < cn; i += 256) {
    const float* p = nbr + (size_t)b * KN * F + cs + i;
    float a = 0.f;
#pragma unroll
    for (int k = 0; k < KN; ++k) a += p[k * F];
    xyc[i] = make_float2(x[b * F + cs + i], a);
  }
  __syncthreads();
  float gx[6], gy[6], acc[6] = {};
#pragma unroll
  for (int j = 0; j < 6; ++j) {
    int g = threadIdx.x + 256 * j;
    int gc = min(g, F - 1);
    const float* p = nbr + (size_t)b * KN * F + gc;
    float a = 0.f;
#pragma unroll
    for (int k = 0; k < KN; ++k) a += p[k * F];
    gx[j] = (g < F) ? x[b * F + gc] : 0.f;
    gy[j] = (g < F) ? a : 0.f;
  }
  if (s == 0) {
#pragma unroll
    for (int j = 0; j < 6; ++j) {
      int g = threadIdx.x + 256 * j;
      if (g < F) ys_out[b * F + g] = gy[j];
    }
  }
#pragma unroll 6
  for (int i = 0; i < cn; ++i) {
    float2 p = xyc[i];
#pragma unroll
    for (int j = 0; j < 6; ++j)
      acc[j] += __builtin_amdgcn_sqrtf(fmaf(gy[j], p.x, gx[j] * p.y));
  }
#pragma unroll
  for (int j = 0; j < 6; ++j) {
    int g = threadIdx.x + 256 * j;
    if (g < F) DP[(size_t)s * BF + b * F + g] = acc[j];
  }
}

__global__ __launch_bounds__(256) void k_y1(const float* __restrict__ x,
                                            const float* __restrict__ ys,
                                            const float* __restrict__ DP,
                                            float* __restrict__ Y1P,
                                            float4* __restrict__ P) {
  __shared__ __align__(16) float4 pl[CH];
  const int b = blockIdx.x, s = blockIdx.y;
  const int cs = s * CH, cn = min(CH, F - cs);
  for (int i = threadIdx.x; i < cn; i += 256) {
    int g = cs + i;
    float d = 0.f;
#pragma unroll
    for (int t = 0; t < SF; ++t) d += DP[(size_t)t * BF + b * F + g];
    float inv = (d > 0.f) ? 1.f / d : 0.f;
    float xv = x[b * F + g], yv = ys[b * F + g];
    float4 pv = make_float4(xv, yv, xv * inv, inv);
    pl[i] = pv;
    P[b * F + g] = pv;
  }
  __syncthreads();
  float fx[6], fy[6], acc[6] = {};
#pragma unroll
  for (int j = 0; j < 6; ++j) {
    int f = threadIdx.x + 256 * j;
    fx[j] = (f < F) ? x[b * F + f] : 0.f;
    fy[j] = (f < F) ? ys[b * F + f] : 0.f;
  }
#pragma unroll 6
  for (int i = 0; i < cn; ++i) {
    float4 p = pl[i];
#pragma unroll
    for (int j = 0; j < 6; ++j)
      acc[j] = fmaf(__builtin_amdgcn_sqrtf(fmaf(fx[j], p.y, fy[j] * p.x)), p.z, acc[j]);
  }
#pragma unroll
  for (int j = 0; j < 6; ++j) {
    int f = threadIdx.x + 256 * j;
    if (f < F) Y1P[(size_t)s * BF + b * F + f] = acc[j];
  }
}

__global__ __launch_bounds__(256) void k_Astats(const float* __restrict__ x,
                                                const float* __restrict__ ys,
                                                const float4* __restrict__ P,
                                                const float* __restrict__ Y1P,
                                                __hip_bfloat16* __restrict__ Ab,
                                                float* __restrict__ y1,
                                                float* __restrict__ st) {
  const int bid = blockIdx.x;
  if (bid < NAL) {
    __shared__ float2 fxy[FT][NB];
    const int gxc = bid % 6, fy = bid / 6;
    const int fbase = fy * FT;
#pragma unroll
    for (int r = 0; r < 3; ++r) {
      int i = threadIdx.x + 256 * r;
      int j = i >> 6, bb = i & 63;
      int f = fbase + j;
      float vx = 0.f, vy = 0.f;
      if (f < F) { vx = x[bb * F + f]; vy = ys[bb * F + f]; }
      fxy[j][bb] = make_float2(vx, vy);
    }
    __syncthreads();
    const int g = gxc * 256 + threadIdx.x;
    if (g >= AbS) return;
    if (g < F) {
      float acc[FT] = {};
      float4 cur[4], nxt[4];
#pragma unroll
      for (int t = 0; t < 4; ++t) cur[t] = P[t * F + g];
      for (int bb = 0; bb < NB; bb += 4) {
        if (bb + 4 < NB) {
#pragma unroll
          for (int t = 0; t < 4; ++t) nxt[t] = P[(bb + 4 + t) * F + g];
        }
#pragma unroll
        for (int t = 0; t < 4; ++t) {
          float4 pc = cur[t];
#pragma unroll
          for (int j = 0; j < FT; ++j) {
            float2 w = fxy[j][bb + t];
            acc[j] = fmaf(__builtin_amdgcn_sqrtf(fmaf(w.x, pc.y, pc.x * w.y)), pc.w, acc[j]);
          }
        }
#pragma unroll
        for (int t = 0; t < 4; ++t) cur[t] = nxt[t];
      }
#pragma unroll
      for (int j = 0; j < FT; ++j) {
        int f = fbase + j;
        if (f < F) Ab[(size_t)f * AbS + g] = __float2bfloat16(acc[j]);
      }
    } else {
#pragma unroll
      for (int j = 0; j < FT; ++j) {
        int f = fbase + j;
        if (f < F) Ab[(size_t)f * AbS + g] = __float2bfloat16(0.f);
      }
    }
  } else {
    const int sid = bid - NAL;
    float sv = 0.f, sq = 0.f;
    for (int i = sid * 256 + threadIdx.x; i < BF; i += NST * 256) {
      float v = x[i];
#pragma unroll
      for (int t = 0; t < SF; ++t) v += Y1P[(size_t)t * BF + i];
      y1[i] = v;
      sv += v; sq += v * v;
    }
#pragma unroll
    for (int o = 32; o; o >>= 1) {
      sv += __shfl_down(sv, o, 64);
      sq += __shfl_down(sq, o, 64);
    }
    __shared__ float ls[4], lq[4];
    int wave = threadIdx.x >> 6, lane = threadIdx.x & 63;
    if (lane == 0) { ls[wave] = sv; lq[wave] = sq; }
    __syncthreads();
    if (threadIdx.x == 0) {
      atomicAdd(&st[0], ls[0] + ls[1] + ls[2] + ls[3]);
      atomicAdd(&st[1], lq[0] + lq[1] + lq[2] + lq[3]);
    }
  }
}

__global__ __launch_bounds__(256, 4) void k_gemm(const ushort* __restrict__ Ab,
                                                 const float* __restrict__ y1,
                                                 const float* __restrict__ st,
                                                 const float* __restrict__ W1,
                                                 const float* __restrict__ g1,
                                                 const float* __restrict__ be1,
                                                 float* __restrict__ G2P) {
  const float mu = st[0] / (float)BF;
  const float var = st[1] / (float)BF - mu * mu;
  const float wa = W1[0], wb = W1[1];
  const float k0 = wa * g1[0] / sqrtf(wa * wa * var + EPS);
  const float k1 = wb * g1[1] / sqrtf(wb * wb * var + EPS);
  const float c0 = -k0 * mu + be1[0];
  const float c1 = -k1 * mu + be1[1];

  __shared__ __align__(16) float Al[32 * 36];
  __shared__ __align__(16) float Hl[32 * 132];
  const int f0 = blockIdx.x * 32;
  const int gs = blockIdx.y * 96;
  const int tid = threadIdx.x;
  const int ffs = tid >> 3, g4s = (tid & 7) * 4;
  const int hb = tid & 7, hg = tid >> 3;
  const int fsub = (tid & 7) * 4, msub = (tid >> 3) * 4;

  uint2 pa; float pyv[8];
  auto loadRegs = [&](int gb) {
    const int f = f0 + ffs;
    pa = make_uint2(0u, 0u);
    if (f < F) pa = *(const uint2*)&Ab[(size_t)f * AbS + gb + g4s];
    const int gl = min(gb + hg, F - 1);
#pragma unroll
    for (int r = 0; r < 8; ++r) pyv[r] = y1[(hb + 8 * r) * F + gl];
  };
  auto storeLDS = [&]() {
    Al[(g4s + 0) * 36 + ffs] = __uint_as_float(pa.x << 16);
    Al[(g4s + 1) * 36 + ffs] = __uint_as_float(pa.x & 0xffff0000u);
    Al[(g4s + 2) * 36 + ffs] = __uint_as_float(pa.y << 16);
    Al[(g4s + 3) * 36 + ffs] = __uint_as_float(pa.y & 0xffff0000u);
#pragma unroll
    for (int r = 0; r < 8; ++r) {
      const int bb = hb + 8 * r;
      const float v = pyv[r];
      float h0 = fmaf(k0, v, c0); h0 = h0 / (1.f + fabsf(h0));
      float h1 = fmaf(k1, v, c1); h1 = h1 / (1.f + fabsf(h1));
      *(float2*)&Hl[hg * 132 + 2 * bb] = make_float2(h0, h1);
    }
  };

  float acc[4][4] = {};
  loadRegs(gs);
  for (int c = 0; c < 3; ++c) {
    if (c) __syncthreads();
    storeLDS();
    __syncthreads();
    if (c < 2) loadRegs(gs + (c + 1) * 32);
#pragma unroll 4
    for (int gi = 0; gi < 32; ++gi) {
      float4 a4 = *(const float4*)&Al[gi * 36 + fsub];
      float4 h4 = *(const float4*)&Hl[gi * 132 + msub];
      float av[4] = {a4.x, a4.y, a4.z, a4.w};
      float hv[4] = {h4.x, h4.y, h4.z, h4.w};
#pragma unroll
      for (int i = 0; i < 4; ++i)
#pragma unroll
        for (int j = 0; j < 4; ++j)
          acc[i][j] = fmaf(av[i], hv[j], acc[i][j]);
    }
  }
  float* dst = G2P + (size_t)blockIdx.y * 128 * F;
#pragma unroll
  for (int i = 0; i < 4; ++i) {
    int f = f0 + fsub + i;
    if (f < F) {
#pragma unroll
      for (int j = 0; j < 4; ++j)
        dst[(msub + j) * F + f] = acc[i][j];
    }
  }
}

__global__ __launch_bounds__(256) void k_stats2(const float* __restrict__ y1,
                                                const float* __restrict__ G2P,
                                                const float* __restrict__ st,
                                                const float* __restrict__ W1,
                                                const float* __restrict__ g1,
                                                const float* __restrict__ be1,
                                                float* __restrict__ y2,
                                                float* __restrict__ stw) {
  const float mu = st[0] / (float)BF;
  const float var = st[1] / (float)BF - mu * mu;
  const float wa = W1[0], wb = W1[1];
  const float k0 = wa * g1[0] / sqrtf(wa * wa * var + EPS);
  const float k1 = wb * g1[1] / sqrtf(wb * wb * var + EPS);
  const float c0 = -k0 * mu + be1[0];
  const float c1 = -k1 * mu + be1[1];

  float su = 0.f, sv = 0.f, suu = 0.f, svv = 0.f, suv = 0.f;
  for (int i = blockIdx.x * 256 + threadIdx.x; i < BF; i += gridDim.x * 256) {
    int b = i / F, f = i - b * F;
    float w = y1[i];
    float h0 = fmaf(k0, w, c0); h0 = h0 / (1.f + fabsf(h0));
    float h1 = fmaf(k1, w, c1); h1 = h1 / (1.f + fabsf(h1));
    int iu = (2 * b) * F + f, iv = iu + F;
    float u = 64.f * h0, v = 64.f * h1;
#pragma unroll
    for (int t = 0; t < SK; ++t) {
      u += G2P[(size_t)t * 128 * F + iu];
      v += G2P[(size_t)t * 128 * F + iv];
    }
    y2[iu] = u; y2[iv] = v;
    su += u; sv += v; suu += u * u; svv += v * v; suv += u * v;
  }
#pragma unroll
  for (int o = 32; o; o >>= 1) {
    su += __shfl_down(su, o, 64);
    sv += __shfl_down(sv, o, 64);
    suu += __shfl_down(suu, o, 64);
    svv += __shfl_down(svv, o, 64);
    suv += __shfl_down(suv, o, 64);
  }
  __shared__ float red[5][4];
  int wave = threadIdx.x >> 6, lane = threadIdx.x & 63;
  if (lane == 0) {
    red[0][wave] = su; red[1][wave] = sv; red[2][wave] = suu;
    red[3][wave] = svv; red[4][wave] = suv;
  }
  __syncthreads();
  if (threadIdx.x == 0) {
#pragma unroll
    for (int m = 0; m < 5; ++m)
      atomicAdd(&stw[2 + m], red[m][0] + red[m][1] + red[m][2] + red[m][3]);
  }
}

__global__ __launch_bounds__(256) void k_out(const float* __restrict__ y2,
                                             const float* __restrict__ st,
                                             const float* __restrict__ W2,
                                             const float* __restrict__ b2,
                                             const float* __restrict__ g2,
                                             const float* __restrict__ be2,
                                             const float* __restrict__ Wc,
                                             const float* __restrict__ bc,
                                             float* __restrict__ out) {
  float n = (float)BF;
  float Eu = st[2] / n, Ev = st[3] / n;
  float Euu = st[4] / n, Evv = st[5] / n, Euv = st[6] / n;
  float cA[2], cB[2], cC[2];
#pragma unroll
  for (int o = 0; o < 2; ++o) {
    float w0 = W2[o * 2 + 0], w1 = W2[o * 2 + 1];
    float mean = w0 * Eu + w1 * Ev + b2[o];
    float Eh2 = w0 * w0 * Euu + 2.f * w0 * w1 * Euv + w1 * w1 * Evv +
                2.f * b2[o] * (w0 * Eu + w1 * Ev) + b2[o] * b2[o];
    float vr = Eh2 - mean * mean;
    float inv = g2[o] / sqrtf(vr + EPS);
    cA[o] = w0 * inv;
    cB[o] = w1 * inv;
    cC[o] = (b2[o] - mean) * inv + be2[o];
  }
  const int b = blockIdx.x;
  float acc[7] = {};
  for (int f = threadIdx.x; f < F; f += 256) {
    float u = y2[(2 * b) * F + f], v = y2[(2 * b + 1) * F + f];
    float h0 = fmaf(cA[0], u, fmaf(cB[0], v, cC[0]));
    h0 = h0 / (1.f + fabsf(h0));
    float h1 = fmaf(cA[1], u, fmaf(cB[1], v, cC[1]));
    h1 = h1 / (1.f + fabsf(h1));
#pragma unroll
    for (int o = 0; o < 7; ++o) acc[o] = fmaf(Wc[o * (2 * F) + f], h0, acc[o]);
#pragma unroll
    for (int o = 0; o < 7; ++o) acc[o] = fmaf(Wc[o * (2 * F) + F + f], h1, acc[o]);
  }
#pragma unroll
  for (int o = 0; o < 7; ++o) {
#pragma unroll
    for (int s = 32; s; s >>= 1) acc[o] += __shfl_down(acc[o], s, 64);
  }
  __shared__ float red[7][4];
  int wave = threadIdx.x >> 6, lane = threadIdx.x & 63;
  if (lane == 0) {
#pragma unroll
    for (int o = 0; o < 7; ++o) red[o][wave] = acc[o];
  }
  __syncthreads();
  if (threadIdx.x < 7) {
    int o = threadIdx.x;
    out[b * 7 + o] = red[o][0] + red[o][1] + red[o][2] + red[o][3] + bc[o];
  }
}

// ===========================================================================
extern "C" void kernel_launch(void* const* d_in, const int* in_sizes, int n_in,
                              void* d_out, int out_size, void* d_ws, size_t ws_size,
                              hipStream_t stream) {
  const float* x    = (const float*)d_in[0];
  const float* nbr  = (const float*)d_in[1];
  const float* W1   = (const float*)d_in[3];
  const float* W2   = (const float*)d_in[5];
  const float* b2   = (const float*)d_in[6];
  const float* g1   = (const float*)d_in[7];
  const float* be1  = (const float*)d_in[8];
  const float* g2   = (const float*)d_in[9];
  const float* be2  = (const float*)d_in[10];
  const float* Wc   = (const float*)d_in[11];
  const float* bc   = (const float*)d_in[12];
  float* out = (float*)d_out;
  float* ws  = (float*)d_ws;

  float*  ys  = ws + O_YS;
  float*  DP  = ws + O_DP;
  float*  Y1P = ws + O_Y1P;
  float4* P   = (float4*)(ws + O_P);
  float*  y1  = ws + O_Y1;
  float*  y2  = ws + O_Y2;
  float*  G2P = ws + O_G2P;
  __hip_bfloat16* Ab = (__hip_bfloat16*)(ws + O_AB);
  float*  st  = ws + O_ST;

  // Decide fused-vs-legacy once: fused needs co-residency. Grid = min(actual
  // per-CU capacity * CUs, NGRID) so phase units (<=1024) never exceed the
  // resident block count by more than grid-stride can absorb.
  static int nblk = -1;
  if (nblk < 0) {
    int dev = 0;
    (void)hipGetDevice(&dev);
    int cus = 0;
    if (hipDeviceGetAttribute(&cus, hipDeviceAttributeMultiprocessorCount, dev) != hipSuccess || cus <= 0)
      cus = 256;
    int nb = 0;
    if (hipOccupancyMaxActiveBlocksPerMultiprocessor(
            &nb, reinterpret_cast<const void*>(&k_fused), 512, 0) != hipSuccess)
      nb = 0;
    long cap = (long)nb * (long)cus;
    long want = (cap >= NGRID) ? NGRID : (cap / 8) * 8;  // barrier needs %8==0
    nblk = (int)want;                                    // <256 => legacy
  }

  if (nblk >= 256) {
    hipMemsetAsync((void*)(ws + O_ST), 0, 2048, stream);  // st + barrier words
    k_fused<<<dim3(nblk), dim3(512), 0, stream>>>(x, nbr, W1, g1, be1, W2, b2,
                                                  g2, be2, Wc, bc, out, ws);
  } else {
    k_D     <<<dim3(NB, SF), 256, 0, stream>>>(x, nbr, DP, ys, st);
    k_y1    <<<dim3(NB, SF), 256, 0, stream>>>(x, ys, DP, Y1P, P);
    k_Astats<<<NAL + NST, 256, 0, stream>>>(x, ys, P, Y1P, Ab, y1, st);
    k_gemm  <<<dim3(45, SK), 256, 0, stream>>>((const ushort*)Ab, y1, st, W1, g1, be1, G2P);
    k_stats2<<<NST, 256, 0, stream>>>(y1, G2P, st, W1, g1, be1, y2, st);
    k_out   <<<NB, 256, 0, stream>>>(y2, st, W2, b2, g2, be2, Wc, bc, out);
  }
}

// Round 5
// 236.381 us; speedup vs baseline: 1.1379x; 1.1379x over previous
//
#include <hip/hip_runtime.h>
#include <hip/hip_bf16.h>
#include <math.h>

constexpr int F   = 1433;
constexpr int NB  = 64;
constexpr int KN  = 8;
constexpr int BF  = NB * F;            // 91712
constexpr float EPS = 1e-5f;

constexpr int SF  = 16;                // splits for k_D / k_y1
constexpr int CH  = 90;                // 16*90 = 1440 >= F
constexpr int AbS = 1440;              // Ab row stride (zero-padded)
constexpr int SK  = 15;                // gemm splits: 15*96 = 1440
constexpr int FT  = 12;                // A f-tile: 120 tiles * 6 gx = 720
constexpr int NA  = 720;
constexpr int NST = 256;               // stats units
constexpr int NGRID = 1024;            // 4 blk/CU * 256 CU (r2-proven)

// Workspace (float offsets); ws is 256 MiB
constexpr int O_YS  = 0;                       // [BF]
constexpr int O_DP  = O_YS + BF;               // [SF*BF] D partials
constexpr int O_Y1P = O_DP + SF * BF;          // [SF*BF] y1 partials
constexpr int O_P   = O_Y1P + SF * BF;         // [4*BF]  float4 (x,ys,w,q)
constexpr int O_Y1  = O_P + 4 * BF;            // [BF]
constexpr int O_Y2  = O_Y1 + BF;               // [2*BF]
constexpr int O_G2P = O_Y2 + 2 * BF;           // [SK*128*F] gemm partials
constexpr int O_AB  = O_G2P + SK * 128 * F;    // [F*AbS halfs] bf16 A
constexpr int O_ST  = O_AB + (F * AbS) / 2;    // [64] stats (memset to 0)
constexpr int O_BAR = O_ST + 64;               // [258] barrier words

// Device-scope (sc1) write-through store: value visible at the L3 coherence
// point once vmcnt drains — no buffer_wbl2 / buffer_inv needed at barriers.
__device__ __forceinline__ void devst(float* p, float v) {
  __hip_atomic_store(p, v, __ATOMIC_RELAXED, __HIP_MEMORY_SCOPE_AGENT);
}
__device__ __forceinline__ void devst16(ushort* p, ushort v) {
  __hip_atomic_store(p, v, __ATOMIC_RELAXED, __HIP_MEMORY_SCOPE_AGENT);
}
__device__ __forceinline__ void devst4(float4* p, float4 v) {
  union { float2 f; unsigned long long u; } lo, hi;
  lo.f = make_float2(v.x, v.y);
  hi.f = make_float2(v.z, v.w);
  unsigned long long* q = (unsigned long long*)p;
  __hip_atomic_store(q + 0, lo.u, __ATOMIC_RELAXED, __HIP_MEMORY_SCOPE_AGENT);
  __hip_atomic_store(q + 1, hi.u, __ATOMIC_RELAXED, __HIP_MEMORY_SCOPE_AGENT);
}
__device__ __forceinline__ float devld(const float* p) {
  return __hip_atomic_load(p, __ATOMIC_RELAXED, __HIP_MEMORY_SCOPE_AGENT);
}

// ---------------------------------------------------------------------------
// Cache-op-free grid barrier (r2-verified at 179 us): relaxed atomics only;
// data coherence via sc1 write-through + __syncthreads vmcnt drain.
// s_sleep(8): ~0.35 us poll period (r2 used 32 -> up to 1.3 us wake lag).
// Requires gridDim.x % 8 == 0 and full co-residency.
// ---------------------------------------------------------------------------
__device__ __forceinline__ void grid_barrier(unsigned* bar, unsigned phase) {
  __syncthreads();                     // drains vmcnt(0): block's sc1 stores at L3
  if (threadIdx.x == 0) {
    const unsigned ngrp = gridDim.x >> 3;
    const unsigned grp = (unsigned)blockIdx.x & 7u;
    unsigned old = __hip_atomic_fetch_add(&bar[grp * 32], 1u,
                                          __ATOMIC_RELAXED, __HIP_MEMORY_SCOPE_AGENT);
    if (old == phase * ngrp - 1u) {
      unsigned m = __hip_atomic_fetch_add(&bar[256], 1u,
                                          __ATOMIC_RELAXED, __HIP_MEMORY_SCOPE_AGENT);
      if (m == phase * 8u - 1u)
        __hip_atomic_store(&bar[257], phase, __ATOMIC_RELAXED, __HIP_MEMORY_SCOPE_AGENT);
    }
    while (__hip_atomic_load(&bar[257], __ATOMIC_RELAXED, __HIP_MEMORY_SCOPE_AGENT) < phase)
      __builtin_amdgcn_s_sleep(8);
  }
  __syncthreads();
}

// ---------------------------------------------------------------------------
// Fused persistent pipeline (r2 geometry, proven 179 us kernel):
// D -> y1/P -> A+stats1 -> gemm -> stats2 -> out.  1024 blocks x 256 thr,
// 4 blk/CU; every phase <= 1024 units so each block runs <= 1 unit.
// ---------------------------------------------------------------------------
__global__ __launch_bounds__(256, 4) void k_fused(
    const float* __restrict__ x, const float* __restrict__ nbr,
    const float* __restrict__ W1, const float* __restrict__ g1,
    const float* __restrict__ be1, const float* __restrict__ W2,
    const float* __restrict__ b2, const float* __restrict__ g2,
    const float* __restrict__ be2, const float* __restrict__ Wc,
    const float* __restrict__ bc, float* __restrict__ out,
    float* __restrict__ ws) {
  float*  ys  = ws + O_YS;
  float*  DP  = ws + O_DP;
  float*  Y1P = ws + O_Y1P;
  float4* P   = (float4*)(ws + O_P);
  float*  y1  = ws + O_Y1;
  float*  y2  = ws + O_Y2;
  float*  G2P = ws + O_G2P;
  ushort* Ab  = (ushort*)(ws + O_AB);
  const ushort* Abu = (const ushort*)(ws + O_AB);
  float*  st  = ws + O_ST;
  unsigned* bar = (unsigned*)(ws + O_BAR);

  __shared__ __align__(16) char smem[21504];   // union of all phase LDS needs
  const int tid = threadIdx.x;
  const int gsz = (int)gridDim.x;

  // ---------------- phase 1: D partials (1024 units) -----------------------
  {
    float2* xyc = (float2*)smem;
    for (int w = blockIdx.x; w < NB * SF; w += gsz) {
      const int b = w & 63, s = w >> 6;
      __syncthreads();                 // guard xyc reuse across w iterations
      const int cs = s * CH, cn = min(CH, F - cs);
      for (int i = tid; i < cn; i += 256) {
        const float* p = nbr + (size_t)b * KN * F + cs + i;
        float a = 0.f;
#pragma unroll
        for (int k = 0; k < KN; ++k) a += p[k * F];
        xyc[i] = make_float2(x[b * F + cs + i], a);
      }
      __syncthreads();
      float gx[6], gy[6], acc[6] = {};
#pragma unroll
      for (int j = 0; j < 6; ++j) {
        int g = tid + 256 * j;
        int gc = min(g, F - 1);
        const float* p = nbr + (size_t)b * KN * F + gc;
        float a = 0.f;
#pragma unroll
        for (int k = 0; k < KN; ++k) a += p[k * F];
        gx[j] = (g < F) ? x[b * F + gc] : 0.f;
        gy[j] = (g < F) ? a : 0.f;
      }
      if (s == 0) {
#pragma unroll
        for (int j = 0; j < 6; ++j) {
          int g = tid + 256 * j;
          if (g < F) devst(&ys[b * F + g], gy[j]);
        }
      }
#pragma unroll 6
      for (int i = 0; i < cn; ++i) {
        float2 p = xyc[i];   // LDS broadcast, conflict-free
#pragma unroll
        for (int j = 0; j < 6; ++j)
          acc[j] += __builtin_amdgcn_sqrtf(fmaf(gy[j], p.x, gx[j] * p.y));
      }
#pragma unroll
      for (int j = 0; j < 6; ++j) {
        int g = tid + 256 * j;
        if (g < F) devst(&DP[(size_t)s * BF + b * F + g], acc[j]);
      }
    }
  }
  grid_barrier(bar, 1u);

  // ---------------- phase 2: y1 partials; D-reduce -> P (1024 units) -------
  {
    float4* pl = (float4*)smem;
    for (int w = blockIdx.x; w < NB * SF; w += gsz) {
      const int b = w & 63, s = w >> 6;
      __syncthreads();                 // guard pl reuse
      const int cs = s * CH, cn = min(CH, F - cs);
      for (int i = tid; i < cn; i += 256) {
        int g = cs + i;
        float d = 0.f;
#pragma unroll
        for (int t = 0; t < SF; ++t) d += DP[(size_t)t * BF + b * F + g];
        float inv = (d > 0.f) ? 1.f / d : 0.f;
        float xv = x[b * F + g], yv = ys[b * F + g];
        float4 pv = make_float4(xv, yv, xv * inv, inv);
        pl[i] = pv;
        devst4(&P[b * F + g], pv);
      }
      __syncthreads();
      float fx[6], fys[6], acc[6] = {};
#pragma unroll
      for (int j = 0; j < 6; ++j) {
        int f = tid + 256 * j;
        fx[j]  = (f < F) ? x[b * F + f] : 0.f;
        fys[j] = (f < F) ? ys[b * F + f] : 0.f;
      }
#pragma unroll 6
      for (int i = 0; i < cn; ++i) {
        float4 p = pl[i];   // broadcast
#pragma unroll
        for (int j = 0; j < 6; ++j)
          acc[j] = fmaf(__builtin_amdgcn_sqrtf(fmaf(fx[j], p.y, fys[j] * p.x)), p.z, acc[j]);
      }
#pragma unroll
      for (int j = 0; j < 6; ++j) {
        int f = tid + 256 * j;
        if (f < F) devst(&Y1P[(size_t)s * BF + b * F + f], acc[j]);
      }
    }
  }
  grid_barrier(bar, 2u);

  // ---------------- phase 3: A-build (720 units) + stats1 (256 units) ------
  {
    for (int w = blockIdx.x; w < NA + NST; w += gsz) {
      __syncthreads();                 // guard smem reuse across w iterations
      if (w < NA) {
        float2 (*fxy)[NB] = (float2(*)[NB])smem;   // 6 KB
        const int gxc = w % 6, fyt = w / 6;
        const int fbase = fyt * FT;
#pragma unroll
        for (int r = 0; r < 3; ++r) {    // FT*NB = 768
          int i = tid + 256 * r;
          int j = i >> 6, bb = i & 63;
          int f = fbase + j;
          float vx = 0.f, vy = 0.f;
          if (f < F) { vx = x[bb * F + f]; vy = ys[bb * F + f]; }
          fxy[j][bb] = make_float2(vx, vy);
        }
        __syncthreads();
        const int g = gxc * 256 + tid;
        if (g < F) {
          float acc[FT] = {};
          float4 cur[4], nxt[4];
#pragma unroll
          for (int t = 0; t < 4; ++t) cur[t] = P[t * F + g];
          for (int bb = 0; bb < NB; bb += 4) {
            if (bb + 4 < NB) {
#pragma unroll
              for (int t = 0; t < 4; ++t) nxt[t] = P[(bb + 4 + t) * F + g];
            }
#pragma unroll
            for (int t = 0; t < 4; ++t) {
              float4 pc = cur[t];
#pragma unroll
              for (int j = 0; j < FT; ++j) {
                float2 wv = fxy[j][bb + t];   // broadcast
                acc[j] = fmaf(__builtin_amdgcn_sqrtf(fmaf(wv.x, pc.y, pc.x * wv.y)), pc.w, acc[j]);
              }
            }
#pragma unroll
            for (int t = 0; t < 4; ++t) cur[t] = nxt[t];
          }
#pragma unroll
          for (int j = 0; j < FT; ++j) {
            int f = fbase + j;
            if (f < F) {
              __hip_bfloat16 hv = __float2bfloat16(acc[j]);
              devst16(&Ab[(size_t)f * AbS + g], *reinterpret_cast<ushort*>(&hv));
            }
          }
        } else if (g < AbS) {            // zero pad cols [F, AbS)
#pragma unroll
          for (int j = 0; j < FT; ++j) {
            int f = fbase + j;
            if (f < F) devst16(&Ab[(size_t)f * AbS + g], (ushort)0);
          }
        }
      } else {
        const int sid = w - NA;
        float sv = 0.f, sq = 0.f;
        for (int i = sid * 256 + tid; i < BF; i += NST * 256) {
          float v = x[i];
#pragma unroll
          for (int t = 0; t < SF; ++t) v += Y1P[(size_t)t * BF + i];
          devst(&y1[i], v);
          sv += v; sq += v * v;
        }
#pragma unroll
        for (int o = 32; o; o >>= 1) {
          sv += __shfl_down(sv, o, 64);
          sq += __shfl_down(sq, o, 64);
        }
        float* ls = (float*)smem;
        float* lq = ls + 4;
        int wave = tid >> 6, lane = tid & 63;
        if (lane == 0) { ls[wave] = sv; lq[wave] = sq; }
        __syncthreads();
        if (tid == 0) {
          atomicAdd(&st[0], ls[0] + ls[1] + ls[2] + ls[3]);
          atomicAdd(&st[1], lq[0] + lq[1] + lq[2] + lq[3]);
        }
      }
    }
  }
  grid_barrier(bar, 3u);

  // BN1 constants: computed once, reused by phases 4 and 5 (registers).
  const float mu  = st[0] / (float)BF;
  const float var = st[1] / (float)BF - mu * mu;
  const float wa = W1[0], wb = W1[1];
  const float k0 = wa * g1[0] / sqrtf(wa * wa * var + EPS);
  const float k1 = wb * g1[1] / sqrtf(wb * wb * var + EPS);
  const float c0 = -k0 * mu + be1[0];
  const float c1 = -k1 * mu + be1[1];

  // ---------------- phase 4: gemm (675 units, <=1 per block) ---------------
  {
    float* Al = (float*)smem;               // 32*36 floats = 4.6 KB
    float* Hl = (float*)(smem + 4608);      // 32*132 floats = 16.9 KB
    const int ffs = tid >> 3, g4s = (tid & 7) * 4;
    const int hb = tid & 7, hg = tid >> 3;
    const int fsub = (tid & 7) * 4, msub = (tid >> 3) * 4;

    for (int w = blockIdx.x; w < 45 * SK; w += gsz) {
      const int fb = w % 45, sk = w / 45;
      const int f0 = fb * 32;
      const int gs = sk * 96;
      __syncthreads();                 // guard Al/Hl reuse across w iterations

      uint2 pa; float pyv[8];
      auto loadRegs = [&](int gb) {
        const int f = f0 + ffs;
        pa = make_uint2(0u, 0u);
        if (f < F) pa = *(const uint2*)&Abu[(size_t)f * AbS + gb + g4s];
        const int gl = min(gb + hg, F - 1);   // pad cols of A are 0
#pragma unroll
        for (int r = 0; r < 8; ++r) pyv[r] = y1[(hb + 8 * r) * F + gl];
      };
      auto storeLDS = [&]() {
        Al[(g4s + 0) * 36 + ffs] = __uint_as_float(pa.x << 16);
        Al[(g4s + 1) * 36 + ffs] = __uint_as_float(pa.x & 0xffff0000u);
        Al[(g4s + 2) * 36 + ffs] = __uint_as_float(pa.y << 16);
        Al[(g4s + 3) * 36 + ffs] = __uint_as_float(pa.y & 0xffff0000u);
#pragma unroll
        for (int r = 0; r < 8; ++r) {
          const int bb = hb + 8 * r;
          const float v = pyv[r];
          float h0 = fmaf(k0, v, c0); h0 = h0 / (1.f + fabsf(h0));
          float h1 = fmaf(k1, v, c1); h1 = h1 / (1.f + fabsf(h1));
          *(float2*)&Hl[hg * 132 + 2 * bb] = make_float2(h0, h1);
        }
      };

      float acc[4][4] = {};
      loadRegs(gs);
      for (int c = 0; c < 3; ++c) {
        if (c) __syncthreads();
        storeLDS();
        __syncthreads();
        if (c < 2) loadRegs(gs + (c + 1) * 32);
#pragma unroll 4
        for (int gi = 0; gi < 32; ++gi) {
          float4 a4 = *(const float4*)&Al[gi * 36 + fsub];
          float4 h4 = *(const float4*)&Hl[gi * 132 + msub];
          float av[4] = {a4.x, a4.y, a4.z, a4.w};
          float hv[4] = {h4.x, h4.y, h4.z, h4.w};
#pragma unroll
          for (int i = 0; i < 4; ++i)
#pragma unroll
            for (int j = 0; j < 4; ++j)
              acc[i][j] = fmaf(av[i], hv[j], acc[i][j]);
        }
      }
      float* dst = G2P + (size_t)sk * 128 * F;
#pragma unroll
      for (int i = 0; i < 4; ++i) {
        int f = f0 + fsub + i;
        if (f < F) {
#pragma unroll
          for (int j = 0; j < 4; ++j)
            devst(&dst[(msub + j) * F + f], acc[i][j]);
        }
      }
    }
  }
  grid_barrier(bar, 4u);

  // ---------------- phase 5: reduce partials + 64*H diag -> y2, moments ----
  {
    float su = 0.f, sv = 0.f, suu = 0.f, svv = 0.f, suv = 0.f;
    for (int i = blockIdx.x * 256 + tid; i < BF; i += gsz * 256) {
      int b = i / F, f = i - b * F;
      float wv = y1[i];
      float h0 = fmaf(k0, wv, c0); h0 = h0 / (1.f + fabsf(h0));
      float h1 = fmaf(k1, wv, c1); h1 = h1 / (1.f + fabsf(h1));
      int iu = (2 * b) * F + f, iv = iu + F;
      float u = 64.f * h0, v = 64.f * h1;
#pragma unroll
      for (int t = 0; t < SK; ++t) {
        u += G2P[(size_t)t * 128 * F + iu];
        v += G2P[(size_t)t * 128 * F + iv];
      }
      devst(&y2[iu], u); devst(&y2[iv], v);
      su += u; sv += v; suu += u * u; svv += v * v; suv += u * v;
    }
#pragma unroll
    for (int o = 32; o; o >>= 1) {
      su  += __shfl_down(su, o, 64);
      sv  += __shfl_down(sv, o, 64);
      suu += __shfl_down(suu, o, 64);
      svv += __shfl_down(svv, o, 64);
      suv += __shfl_down(suv, o, 64);
    }
    float (*red)[4] = (float(*)[4])smem;
    int wave = tid >> 6, lane = tid & 63;
    if (lane == 0) {
      red[0][wave] = su; red[1][wave] = sv; red[2][wave] = suu;
      red[3][wave] = svv; red[4][wave] = suv;
    }
    __syncthreads();
    if (tid == 0) {
#pragma unroll
      for (int m = 0; m < 5; ++m)
        atomicAdd(&st[2 + m], red[m][0] + red[m][1] + red[m][2] + red[m][3]);
    }
  }
  grid_barrier(bar, 5u);

  // ---------------- phase 6: final classifier (64 units, direct store) -----
  {
    float n = (float)BF;
    // st[2..6] share a cache line with st[0..1] (plain-loaded above) — sc1
    // loads dodge the stale-L2-line hazard.
    float Eu = devld(&st[2]) / n, Ev = devld(&st[3]) / n;
    float Euu = devld(&st[4]) / n, Evv = devld(&st[5]) / n, Euv = devld(&st[6]) / n;
    float cA[2], cB[2], cC[2];
#pragma unroll
    for (int o = 0; o < 2; ++o) {
      float w0 = W2[o * 2 + 0], w1 = W2[o * 2 + 1];
      float mean = w0 * Eu + w1 * Ev + b2[o];
      float Eh2 = w0 * w0 * Euu + 2.f * w0 * w1 * Euv + w1 * w1 * Evv +
                  2.f * b2[o] * (w0 * Eu + w1 * Ev) + b2[o] * b2[o];
      float vr = Eh2 - mean * mean;
      float inv = g2[o] / sqrtf(vr + EPS);
      cA[o] = w0 * inv;
      cB[o] = w1 * inv;
      cC[o] = (b2[o] - mean) * inv + be2[o];
    }
    float (*red)[4] = (float(*)[4])smem;
    for (int w = blockIdx.x; w < NB; w += gsz) {
      const int b = w;
      float acc[7] = {};
      for (int f = tid; f < F; f += 256) {
        float u = y2[(2 * b) * F + f], v = y2[(2 * b + 1) * F + f];
        float h0 = fmaf(cA[0], u, fmaf(cB[0], v, cC[0]));
        h0 = h0 / (1.f + fabsf(h0));
        float h1 = fmaf(cA[1], u, fmaf(cB[1], v, cC[1]));
        h1 = h1 / (1.f + fabsf(h1));
#pragma unroll
        for (int o = 0; o < 7; ++o)
          acc[o] = fmaf(Wc[o * (2 * F) + f], h0,
                        fmaf(Wc[o * (2 * F) + F + f], h1, acc[o]));
      }
#pragma unroll
      for (int o = 0; o < 7; ++o) {
#pragma unroll
        for (int s2 = 32; s2; s2 >>= 1) acc[o] += __shfl_down(acc[o], s2, 64);
      }
      __syncthreads();
      int wave = tid >> 6, lane = tid & 63;
      if (lane == 0) {
#pragma unroll
        for (int o = 0; o < 7; ++o) red[o][wave] = acc[o];
      }
      __syncthreads();
      if (tid < 7)
        out[b * 7 + tid] =
            red[tid][0] + red[tid][1] + red[tid][2] + red[tid][3] + bc[tid];
    }
  }
}

// ===========================================================================
// Legacy multi-kernel fallback (205-us baseline path) — used only if the
// fused kernel cannot be co-resident at >=256 blocks.
// ===========================================================================
__global__ __launch_bounds__(256) void k_D(const float* __restrict__ x,
                                           const float* __restrict__ nbr,
                                           float* __restrict__ DP,
                                           float* __restrict__ ys_out,
                                           float* __restrict__ st) {
  const int b = blockIdx.x, s = blockIdx.y;
  if (b == 0 && s == 0 && threadIdx.x < 64) st[threadIdx.x] = 0.f;
  __shared__ __align__(8) float2 xyc[CH];
  const int cs = s * CH, cn = min(CH, F - cs);
  for (int i = threadIdx.x; i < cn; i += 256) {
    const float* p = nbr + (size_t)b * KN * F + cs + i;
    float a = 0.f;
#pragma unroll
    for (int k = 0; k < KN; ++k) a += p[k * F];
    xyc[i] = make_float2(x[b * F + cs + i], a);
  }
  __syncthreads();
  float gx[6], gy[6], acc[6] = {};
#pragma unroll
  for (int j = 0; j < 6; ++j) {
    int g = threadIdx.x + 256 * j;
    int gc = min(g, F - 1);
    const float* p = nbr + (size_t)b * KN * F + gc;
    float a = 0.f;
#pragma unroll
    for (int k = 0; k < KN; ++k) a += p[k * F];
    gx[j] = (g < F) ? x[b * F + gc] : 0.f;
    gy[j] = (g < F) ? a : 0.f;
  }
  if (s == 0) {
#pragma unroll
    for (int j = 0; j < 6; ++j) {
      int g = threadIdx.x + 256 * j;
      if (g < F) ys_out[b * F + g] = gy[j];
    }
  }
#pragma unroll 6
  for (int i = 0; i < cn; ++i) {
    float2 p = xyc[i];
#pragma unroll
    for (int j = 0; j < 6; ++j)
      acc[j] += __builtin_amdgcn_sqrtf(fmaf(gy[j], p.x, gx[j] * p.y));
  }
#pragma unroll
  for (int j = 0; j < 6; ++j) {
    int g = threadIdx.x + 256 * j;
    if (g < F) DP[(size_t)s * BF + b * F + g] = acc[j];
  }
}

__global__ __launch_bounds__(256) void k_y1(const float* __restrict__ x,
                                            const float* __restrict__ ys,
                                            const float* __restrict__ DP,
                                            float* __restrict__ Y1P,
                                            float4* __restrict__ P) {
  __shared__ __align__(16) float4 pl[CH];
  const int b = blockIdx.x, s = blockIdx.y;
  const int cs = s * CH, cn = min(CH, F - cs);
  for (int i = threadIdx.x; i < cn; i += 256) {
    int g = cs + i;
    float d = 0.f;
#pragma unroll
    for (int t = 0; t < SF; ++t) d += DP[(size_t)t * BF + b * F + g];
    float inv = (d > 0.f) ? 1.f / d : 0.f;
    float xv = x[b * F + g], yv = ys[b * F + g];
    float4 pv = make_float4(xv, yv, xv * inv, inv);
    pl[i] = pv;
    P[b * F + g] = pv;
  }
  __syncthreads();
  float fx[6], fy[6], acc[6] = {};
#pragma unroll
  for (int j = 0; j < 6; ++j) {
    int f = threadIdx.x + 256 * j;
    fx[j] = (f < F) ? x[b * F + f] : 0.f;
    fy[j] = (f < F) ? ys[b * F + f] : 0.f;
  }
#pragma unroll 6
  for (int i = 0; i < cn; ++i) {
    float4 p = pl[i];
#pragma unroll
    for (int j = 0; j < 6; ++j)
      acc[j] = fmaf(__builtin_amdgcn_sqrtf(fmaf(fx[j], p.y, fy[j] * p.x)), p.z, acc[j]);
  }
#pragma unroll
  for (int j = 0; j < 6; ++j) {
    int f = threadIdx.x + 256 * j;
    if (f < F) Y1P[(size_t)s * BF + b * F + f] = acc[j];
  }
}

__global__ __launch_bounds__(256) void k_Astats(const float* __restrict__ x,
                                                const float* __restrict__ ys,
                                                const float4* __restrict__ P,
                                                const float* __restrict__ Y1P,
                                                __hip_bfloat16* __restrict__ Ab,
                                                float* __restrict__ y1,
                                                float* __restrict__ st) {
  const int bid = blockIdx.x;
  if (bid < NA) {
    __shared__ float2 fxy[FT][NB];
    const int gxc = bid % 6, fy = bid / 6;
    const int fbase = fy * FT;
#pragma unroll
    for (int r = 0; r < 3; ++r) {
      int i = threadIdx.x + 256 * r;
      int j = i >> 6, bb = i & 63;
      int f = fbase + j;
      float vx = 0.f, vy = 0.f;
      if (f < F) { vx = x[bb * F + f]; vy = ys[bb * F + f]; }
      fxy[j][bb] = make_float2(vx, vy);
    }
    __syncthreads();
    const int g = gxc * 256 + threadIdx.x;
    if (g >= AbS) return;
    if (g < F) {
      float acc[FT] = {};
      float4 cur[4], nxt[4];
#pragma unroll
      for (int t = 0; t < 4; ++t) cur[t] = P[t * F + g];
      for (int bb = 0; bb < NB; bb += 4) {
        if (bb + 4 < NB) {
#pragma unroll
          for (int t = 0; t < 4; ++t) nxt[t] = P[(bb + 4 + t) * F + g];
        }
#pragma unroll
        for (int t = 0; t < 4; ++t) {
          float4 pc = cur[t];
#pragma unroll
          for (int j = 0; j < FT; ++j) {
            float2 w = fxy[j][bb + t];
            acc[j] = fmaf(__builtin_amdgcn_sqrtf(fmaf(w.x, pc.y, pc.x * w.y)), pc.w, acc[j]);
          }
        }
#pragma unroll
        for (int t = 0; t < 4; ++t) cur[t] = nxt[t];
      }
#pragma unroll
      for (int j = 0; j < FT; ++j) {
        int f = fbase + j;
        if (f < F) Ab[(size_t)f * AbS + g] = __float2bfloat16(acc[j]);
      }
    } else {
#pragma unroll
      for (int j = 0; j < FT; ++j) {
        int f = fbase + j;
        if (f < F) Ab[(size_t)f * AbS + g] = __float2bfloat16(0.f);
      }
    }
  } else {
    const int sid = bid - NA;
    float sv = 0.f, sq = 0.f;
    for (int i = sid * 256 + threadIdx.x; i < BF; i += NST * 256) {
      float v = x[i];
#pragma unroll
      for (int t = 0; t < SF; ++t) v += Y1P[(size_t)t * BF + i];
      y1[i] = v;
      sv += v; sq += v * v;
    }
#pragma unroll
    for (int o = 32; o; o >>= 1) {
      sv += __shfl_down(sv, o, 64);
      sq += __shfl_down(sq, o, 64);
    }
    __shared__ float ls[4], lq[4];
    int wave = threadIdx.x >> 6, lane = threadIdx.x & 63;
    if (lane == 0) { ls[wave] = sv; lq[wave] = sq; }
    __syncthreads();
    if (threadIdx.x == 0) {
      atomicAdd(&st[0], ls[0] + ls[1] + ls[2] + ls[3]);
      atomicAdd(&st[1], lq[0] + lq[1] + lq[2] + lq[3]);
    }
  }
}

__global__ __launch_bounds__(256, 4) void k_gemm(const ushort* __restrict__ Ab,
                                                 const float* __restrict__ y1,
                                                 const float* __restrict__ st,
                                                 const float* __restrict__ W1,
                                                 const float* __restrict__ g1,
                                                 const float* __restrict__ be1,
                                                 float* __restrict__ G2P) {
  const float mu = st[0] / (float)BF;
  const float var = st[1] / (float)BF - mu * mu;
  const float wa = W1[0], wb = W1[1];
  const float k0 = wa * g1[0] / sqrtf(wa * wa * var + EPS);
  const float k1 = wb * g1[1] / sqrtf(wb * wb * var + EPS);
  const float c0 = -k0 * mu + be1[0];
  const float c1 = -k1 * mu + be1[1];

  __shared__ __align__(16) float Al[32 * 36];
  __shared__ __align__(16) float Hl[32 * 132];
  const int f0 = blockIdx.x * 32;
  const int gs = blockIdx.y * 96;
  const int tid = threadIdx.x;
  const int ffs = tid >> 3, g4s = (tid & 7) * 4;
  const int hb = tid & 7, hg = tid >> 3;
  const int fsub = (tid & 7) * 4, msub = (tid >> 3) * 4;

  uint2 pa; float pyv[8];
  auto loadRegs = [&](int gb) {
    const int f = f0 + ffs;
    pa = make_uint2(0u, 0u);
    if (f < F) pa = *(const uint2*)&Ab[(size_t)f * AbS + gb + g4s];
    const int gl = min(gb + hg, F - 1);
#pragma unroll
    for (int r = 0; r < 8; ++r) pyv[r] = y1[(hb + 8 * r) * F + gl];
  };
  auto storeLDS = [&]() {
    Al[(g4s + 0) * 36 + ffs] = __uint_as_float(pa.x << 16);
    Al[(g4s + 1) * 36 + ffs] = __uint_as_float(pa.x & 0xffff0000u);
    Al[(g4s + 2) * 36 + ffs] = __uint_as_float(pa.y << 16);
    Al[(g4s + 3) * 36 + ffs] = __uint_as_float(pa.y & 0xffff0000u);
#pragma unroll
    for (int r = 0; r < 8; ++r) {
      const int bb = hb + 8 * r;
      const float v = pyv[r];
      float h0 = fmaf(k0, v, c0); h0 = h0 / (1.f + fabsf(h0));
      float h1 = fmaf(k1, v, c1); h1 = h1 / (1.f + fabsf(h1));
      *(float2*)&Hl[hg * 132 + 2 * bb] = make_float2(h0, h1);
    }
  };

  float acc[4][4] = {};
  loadRegs(gs);
  for (int c = 0; c < 3; ++c) {
    if (c) __syncthreads();
    storeLDS();
    __syncthreads();
    if (c < 2) loadRegs(gs + (c + 1) * 32);
#pragma unroll 4
    for (int gi = 0; gi < 32; ++gi) {
      float4 a4 = *(const float4*)&Al[gi * 36 + fsub];
      float4 h4 = *(const float4*)&Hl[gi * 132 + msub];
      float av[4] = {a4.x, a4.y, a4.z, a4.w};
      float hv[4] = {h4.x, h4.y, h4.z, h4.w};
#pragma unroll
      for (int i = 0; i < 4; ++i)
#pragma unroll
        for (int j = 0; j < 4; ++j)
          acc[i][j] = fmaf(av[i], hv[j], acc[i][j]);
    }
  }
  float* dst = G2P + (size_t)blockIdx.y * 128 * F;
#pragma unroll
  for (int i = 0; i < 4; ++i) {
    int f = f0 + fsub + i;
    if (f < F) {
#pragma unroll
      for (int j = 0; j < 4; ++j)
        dst[(msub + j) * F + f] = acc[i][j];
    }
  }
}

__global__ __launch_bounds__(256) void k_stats2(const float* __restrict__ y1,
                                                const float* __restrict__ G2P,
                                                const float* __restrict__ st,
                                                const float* __restrict__ W1,
                                                const float* __restrict__ g1,
                                                const float* __restrict__ be1,
                                                float* __restrict__ y2,
                                                float* __restrict__ stw) {
  const float mu = st[0] / (float)BF;
  const float var = st[1] / (float)BF - mu * mu;
  const float wa = W1[0], wb = W1[1];
  const float k0 = wa * g1[0] / sqrtf(wa * wa * var + EPS);
  const float k1 = wb * g1[1] / sqrtf(wb * wb * var + EPS);
  const float c0 = -k0 * mu + be1[0];
  const float c1 = -k1 * mu + be1[1];

  float su = 0.f, sv = 0.f, suu = 0.f, svv = 0.f, suv = 0.f;
  for (int i = blockIdx.x * 256 + threadIdx.x; i < BF; i += gridDim.x * 256) {
    int b = i / F, f = i - b * F;
    float w = y1[i];
    float h0 = fmaf(k0, w, c0); h0 = h0 / (1.f + fabsf(h0));
    float h1 = fmaf(k1, w, c1); h1 = h1 / (1.f + fabsf(h1));
    int iu = (2 * b) * F + f, iv = iu + F;
    float u = 64.f * h0, v = 64.f * h1;
#pragma unroll
    for (int t = 0; t < SK; ++t) {
      u += G2P[(size_t)t * 128 * F + iu];
      v += G2P[(size_t)t * 128 * F + iv];
    }
    y2[iu] = u; y2[iv] = v;
    su += u; sv += v; suu += u * u; svv += v * v; suv += u * v;
  }
#pragma unroll
  for (int o = 32; o; o >>= 1) {
    su += __shfl_down(su, o, 64);
    sv += __shfl_down(sv, o, 64);
    suu += __shfl_down(suu, o, 64);
    svv += __shfl_down(svv, o, 64);
    suv += __shfl_down(suv, o, 64);
  }
  __shared__ float red[5][4];
  int wave = threadIdx.x >> 6, lane = threadIdx.x & 63;
  if (lane == 0) {
    red[0][wave] = su; red[1][wave] = sv; red[2][wave] = suu;
    red[3][wave] = svv; red[4][wave] = suv;
  }
  __syncthreads();
  if (threadIdx.x == 0) {
#pragma unroll
    for (int m = 0; m < 5; ++m)
      atomicAdd(&stw[2 + m], red[m][0] + red[m][1] + red[m][2] + red[m][3]);
  }
}

__global__ __launch_bounds__(256) void k_out(const float* __restrict__ y2,
                                             const float* __restrict__ st,
                                             const float* __restrict__ W2,
                                             const float* __restrict__ b2,
                                             const float* __restrict__ g2,
                                             const float* __restrict__ be2,
                                             const float* __restrict__ Wc,
                                             const float* __restrict__ bc,
                                             float* __restrict__ out) {
  float n = (float)BF;
  float Eu = st[2] / n, Ev = st[3] / n;
  float Euu = st[4] / n, Evv = st[5] / n, Euv = st[6] / n;
  float cA[2], cB[2], cC[2];
#pragma unroll
  for (int o = 0; o < 2; ++o) {
    float w0 = W2[o * 2 + 0], w1 = W2[o * 2 + 1];
    float mean = w0 * Eu + w1 * Ev + b2[o];
    float Eh2 = w0 * w0 * Euu + 2.f * w0 * w1 * Euv + w1 * w1 * Evv +
                2.f * b2[o] * (w0 * Eu + w1 * Ev) + b2[o] * b2[o];
    float vr = Eh2 - mean * mean;
    float inv = g2[o] / sqrtf(vr + EPS);
    cA[o] = w0 * inv;
    cB[o] = w1 * inv;
    cC[o] = (b2[o] - mean) * inv + be2[o];
  }
  const int b = blockIdx.x;
  float acc[7] = {};
  for (int f = threadIdx.x; f < F; f += 256) {
    float u = y2[(2 * b) * F + f], v = y2[(2 * b + 1) * F + f];
    float h0 = fmaf(cA[0], u, fmaf(cB[0], v, cC[0]));
    h0 = h0 / (1.f + fabsf(h0));
    float h1 = fmaf(cA[1], u, fmaf(cB[1], v, cC[1]));
    h1 = h1 / (1.f + fabsf(h1));
#pragma unroll
    for (int o = 0; o < 7; ++o) acc[o] = fmaf(Wc[o * (2 * F) + f], h0, acc[o]);
#pragma unroll
    for (int o = 0; o < 7; ++o) acc[o] = fmaf(Wc[o * (2 * F) + F + f], h1, acc[o]);
  }
#pragma unroll
  for (int o = 0; o < 7; ++o) {
#pragma unroll
    for (int s = 32; s; s >>= 1) acc[o] += __shfl_down(acc[o], s, 64);
  }
  __shared__ float red[7][4];
  int wave = threadIdx.x >> 6, lane = threadIdx.x & 63;
  if (lane == 0) {
#pragma unroll
    for (int o = 0; o < 7; ++o) red[o][wave] = acc[o];
  }
  __syncthreads();
  if (threadIdx.x < 7) {
    int o = threadIdx.x;
    out[b * 7 + o] = red[o][0] + red[o][1] + red[o][2] + red[o][3] + bc[o];
  }
}

// ===========================================================================
extern "C" void kernel_launch(void* const* d_in, const int* in_sizes, int n_in,
                              void* d_out, int out_size, void* d_ws, size_t ws_size,
                              hipStream_t stream) {
  const float* x    = (const float*)d_in[0];
  const float* nbr  = (const float*)d_in[1];
  const float* W1   = (const float*)d_in[3];
  const float* W2   = (const float*)d_in[5];
  const float* b2   = (const float*)d_in[6];
  const float* g1   = (const float*)d_in[7];
  const float* be1  = (const float*)d_in[8];
  const float* g2   = (const float*)d_in[9];
  const float* be2  = (const float*)d_in[10];
  const float* Wc   = (const float*)d_in[11];
  const float* bc   = (const float*)d_in[12];
  float* out = (float*)d_out;
  float* ws  = (float*)d_ws;

  float*  ys  = ws + O_YS;
  float*  DP  = ws + O_DP;
  float*  Y1P = ws + O_Y1P;
  float4* P   = (float4*)(ws + O_P);
  float*  y1  = ws + O_Y1;
  float*  y2  = ws + O_Y2;
  float*  G2P = ws + O_G2P;
  __hip_bfloat16* Ab = (__hip_bfloat16*)(ws + O_AB);
  float*  st  = ws + O_ST;

  // Decide fused-vs-legacy once: fused needs co-residency at 1024 blocks.
  static int nblk = -1;
  if (nblk < 0) {
    int dev = 0;
    (void)hipGetDevice(&dev);
    int cus = 0;
    if (hipDeviceGetAttribute(&cus, hipDeviceAttributeMultiprocessorCount, dev) != hipSuccess || cus <= 0)
      cus = 256;
    int nb = 0;
    if (hipOccupancyMaxActiveBlocksPerMultiprocessor(
            &nb, reinterpret_cast<const void*>(&k_fused), 256, 0) != hipSuccess)
      nb = 0;
    long cap = (long)nb * (long)cus;
    long want = (cap >= NGRID) ? NGRID : (cap / 8) * 8;  // barrier needs %8==0
    nblk = (int)want;                                    // <256 => legacy
  }

  if (nblk >= 256) {
    // Single 2 KiB aux fill: st (7 accumulators) + barrier words. Harness
    // re-poisons ws between iterations, so this must run every launch.
    hipMemsetAsync((void*)(ws + O_ST), 0, 2048, stream);
    k_fused<<<dim3(nblk), dim3(256), 0, stream>>>(x, nbr, W1, g1, be1, W2, b2,
                                                  g2, be2, Wc, bc, out, ws);
  } else {
    k_D     <<<dim3(NB, SF), 256, 0, stream>>>(x, nbr, DP, ys, st);
    k_y1    <<<dim3(NB, SF), 256, 0, stream>>>(x, ys, DP, Y1P, P);
    k_Astats<<<NA + NST, 256, 0, stream>>>(x, ys, P, Y1P, Ab, y1, st);
    k_gemm  <<<dim3(45, SK), 256, 0, stream>>>((const ushort*)Ab, y1, st, W1, g1, be1, G2P);
    k_stats2<<<NST, 256, 0, stream>>>(y1, G2P, st, W1, g1, be1, y2, st);
    k_out   <<<NB, 256, 0, stream>>>(y2, st, W2, b2, g2, be2, Wc, bc, out);
  }
}

// Round 6
// 205.872 us; speedup vs baseline: 1.3065x; 1.1482x over previous
//
#include <hip/hip_runtime.h>
#include <hip/hip_bf16.h>
#include <math.h>

constexpr int F   = 1433;
constexpr int NB  = 64;
constexpr int KN  = 8;
constexpr int BF  = NB * F;            // 91712
constexpr float EPS = 1e-5f;

constexpr int SF  = 16;                // splits for k_D / k_y1
constexpr int CH  = 90;                // 16*90 = 1440 >= F
constexpr int AbS = 1440;              // Ab row stride (zero-padded)
constexpr int SK  = 9;                 // gemm splits: 9*160 = 1440
constexpr int FT  = 12;                // A f-tile: 120 tiles * 6 gx = 720
constexpr int NA  = 720;
constexpr int NST = 256;               // stats blocks

// Workspace (float offsets); ws is 256 MiB
constexpr int O_YS  = 0;                       // [BF]
constexpr int O_DP  = O_YS + BF;               // [SF*BF] D partials
constexpr int O_Y1P = O_DP + SF * BF;          // [SF*BF] y1 partials
constexpr int O_P   = O_Y1P + SF * BF;         // [4*BF]  float4 (x,ys,w,q)
constexpr int O_Y1  = O_P + 4 * BF;            // [BF]
constexpr int O_Y2  = O_Y1 + BF;               // [2*BF]
constexpr int O_G2P = O_Y2 + 2 * BF;           // [SK*128*F] gemm partials
constexpr int O_AB  = O_G2P + SK * 128 * F;    // [F*AbS halfs] bf16 A
constexpr int O_ST  = O_AB + (F * AbS) / 2;    // [64] stats

// ---------------- K0: ys[b,g] = sum_k nbr[b,k,g]; zero st -----------------
// nbr read exactly once (2.9 MB). Replaces the 16x-redundant per-block
// recompute that dominated k_D's load count.
__global__ __launch_bounds__(256) void k_ys(const float* __restrict__ nbr,
                                            float* __restrict__ ys,
                                            float* __restrict__ st) {
  const int b = blockIdx.x, q = blockIdx.y;
  if (b == 0 && q == 0 && threadIdx.x < 64) st[threadIdx.x] = 0.f;
  const int g = q * 256 + threadIdx.x;
  if (g < F) {
    const float* p = nbr + (size_t)b * KN * F + g;
    float a = 0.f;
#pragma unroll
    for (int k = 0; k < KN; ++k) a += p[k * F];
    ys[b * F + g] = a;
  }
}

// ---------------- K1: D partials (reads precomputed ys) -------------------
// DP[s][b,g] = sum_{f in chunk s} sqrt(ys_g*x_f + x_g*ys_f)
__global__ __launch_bounds__(256) void k_D(const float* __restrict__ x,
                                           const float* __restrict__ ys,
                                           float* __restrict__ DP) {
  const int b = blockIdx.x, s = blockIdx.y;
  __shared__ __align__(8) float2 xyc[CH];
  const int cs = s * CH, cn = min(CH, F - cs);
  for (int i = threadIdx.x; i < cn; i += 256)
    xyc[i] = make_float2(x[b * F + cs + i], ys[b * F + cs + i]);
  __syncthreads();
  float gx[6], gy[6], acc[6] = {};
#pragma unroll
  for (int j = 0; j < 6; ++j) {
    int g = threadIdx.x + 256 * j;
    int gc = min(g, F - 1);
    gx[j] = (g < F) ? x[b * F + gc] : 0.f;
    gy[j] = (g < F) ? ys[b * F + gc] : 0.f;
  }
#pragma unroll 6
  for (int i = 0; i < cn; ++i) {
    float2 p = xyc[i];   // broadcast, conflict-free
#pragma unroll
    for (int j = 0; j < 6; ++j)
      acc[j] += __builtin_amdgcn_sqrtf(fmaf(gy[j], p.x, gx[j] * p.y));
  }
#pragma unroll
  for (int j = 0; j < 6; ++j) {
    int g = threadIdx.x + 256 * j;
    if (g < F) DP[(size_t)s * BF + b * F + g] = acc[j];
  }
}

// ---------------- K2: y1 partials; D-reduce -> P for own chunk -------------
__global__ __launch_bounds__(256) void k_y1(const float* __restrict__ x,
                                            const float* __restrict__ ys,
                                            const float* __restrict__ DP,
                                            float* __restrict__ Y1P,
                                            float4* __restrict__ P) {
  __shared__ __align__(16) float4 pl[CH];
  const int b = blockIdx.x, s = blockIdx.y;
  const int cs = s * CH, cn = min(CH, F - cs);
  for (int i = threadIdx.x; i < cn; i += 256) {
    int g = cs + i;
    float d = 0.f;
#pragma unroll
    for (int t = 0; t < SF; ++t) d += DP[(size_t)t * BF + b * F + g];
    float inv = (d > 0.f) ? 1.f / d : 0.f;
    float xv = x[b * F + g], yv = ys[b * F + g];
    float4 pv = make_float4(xv, yv, xv * inv, inv);
    pl[i] = pv;
    P[b * F + g] = pv;
  }
  __syncthreads();
  float fx[6], fy[6], acc[6] = {};
#pragma unroll
  for (int j = 0; j < 6; ++j) {
    int f = threadIdx.x + 256 * j;
    fx[j] = (f < F) ? x[b * F + f] : 0.f;
    fy[j] = (f < F) ? ys[b * F + f] : 0.f;
  }
#pragma unroll 6
  for (int i = 0; i < cn; ++i) {
    float4 p = pl[i];   // broadcast
#pragma unroll
    for (int j = 0; j < 6; ++j)
      acc[j] = fmaf(__builtin_amdgcn_sqrtf(fmaf(fx[j], p.y, fy[j] * p.x)), p.z, acc[j]);
  }
#pragma unroll
  for (int j = 0; j < 6; ++j) {
    int f = threadIdx.x + 256 * j;
    if (f < F) Y1P[(size_t)s * BF + b * F + f] = acc[j];
  }
}

// ---------------- K3: fused A-build (720 blocks) + stats1 (256 blocks) -----
__global__ __launch_bounds__(256) void k_Astats(const float* __restrict__ x,
                                                const float* __restrict__ ys,
                                                const float4* __restrict__ P,
                                                const float* __restrict__ Y1P,
                                                __hip_bfloat16* __restrict__ Ab,
                                                float* __restrict__ y1,
                                                float* __restrict__ st) {
  const int bid = blockIdx.x;
  if (bid < NA) {
    __shared__ float2 fxy[FT][NB];   // 6 KB
    const int gxc = bid % 6, fy = bid / 6;
    const int fbase = fy * FT;
#pragma unroll
    for (int r = 0; r < 3; ++r) {    // FT*NB = 768
      int i = threadIdx.x + 256 * r;
      int j = i >> 6, bb = i & 63;
      int f = fbase + j;
      float vx = 0.f, vy = 0.f;
      if (f < F) { vx = x[bb * F + f]; vy = ys[bb * F + f]; }
      fxy[j][bb] = make_float2(vx, vy);
    }
    __syncthreads();
    const int g = gxc * 256 + threadIdx.x;
    if (g >= AbS) return;
    if (g < F) {
      float acc[FT] = {};
      float4 cur[4], nxt[4];
#pragma unroll
      for (int t = 0; t < 4; ++t) cur[t] = P[t * F + g];       // b = 0..3
      for (int bb = 0; bb < NB; bb += 4) {
        if (bb + 4 < NB) {
#pragma unroll
          for (int t = 0; t < 4; ++t) nxt[t] = P[(bb + 4 + t) * F + g];
        }
#pragma unroll
        for (int t = 0; t < 4; ++t) {
          float4 pc = cur[t];
#pragma unroll
          for (int j = 0; j < FT; ++j) {
            float2 w = fxy[j][bb + t];   // broadcast
            acc[j] = fmaf(__builtin_amdgcn_sqrtf(fmaf(w.x, pc.y, pc.x * w.y)), pc.w, acc[j]);
          }
        }
#pragma unroll
        for (int t = 0; t < 4; ++t) cur[t] = nxt[t];
      }
#pragma unroll
      for (int j = 0; j < FT; ++j) {
        int f = fbase + j;
        if (f < F) Ab[(size_t)f * AbS + g] = __float2bfloat16(acc[j]);
      }
    } else {                         // zero pad cols [F, AbS)
#pragma unroll
      for (int j = 0; j < FT; ++j) {
        int f = fbase + j;
        if (f < F) Ab[(size_t)f * AbS + g] = __float2bfloat16(0.f);
      }
    }
  } else {
    const int sid = bid - NA;
    float sv = 0.f, sq = 0.f;
    for (int i = sid * 256 + threadIdx.x; i < BF; i += NST * 256) {
      float v = x[i];
#pragma unroll
      for (int t = 0; t < SF; ++t) v += Y1P[(size_t)t * BF + i];
      y1[i] = v;
      sv += v; sq += v * v;
    }
#pragma unroll
    for (int o = 32; o; o >>= 1) {
      sv += __shfl_down(sv, o, 64);
      sq += __shfl_down(sq, o, 64);
    }
    __shared__ float ls[4], lq[4];
    int wave = threadIdx.x >> 6, lane = threadIdx.x & 63;
    if (lane == 0) { ls[wave] = sv; lq[wave] = sq; }
    __syncthreads();
    if (threadIdx.x == 0) {
      atomicAdd(&st[0], ls[0] + ls[1] + ls[2] + ls[3]);
      atomicAdd(&st[1], lq[0] + lq[1] + lq[2] + lq[3]);
    }
  }
}

// ---------------- K4: gemm, 5 chunks/block (SK=9), 4 blocks/CU ------------
__global__ __launch_bounds__(256, 4) void k_gemm(const ushort* __restrict__ Ab,
                                                 const float* __restrict__ y1,
                                                 const float* __restrict__ st,
                                                 const float* __restrict__ W1,
                                                 const float* __restrict__ g1,
                                                 const float* __restrict__ be1,
                                                 float* __restrict__ G2P) {
  const float mu = st[0] / (float)BF;
  const float var = st[1] / (float)BF - mu * mu;
  const float wa = W1[0], wb = W1[1];
  const float k0 = wa * g1[0] / sqrtf(wa * wa * var + EPS);
  const float k1 = wb * g1[1] / sqrtf(wb * wb * var + EPS);
  const float c0 = -k0 * mu + be1[0];
  const float c1 = -k1 * mu + be1[1];

  __shared__ __align__(16) float Al[32 * 36];    // 4.6 KB
  __shared__ __align__(16) float Hl[32 * 132];   // 16.9 KB
  const int f0 = blockIdx.x * 32;
  const int gs = blockIdx.y * 160;               // SK=9 chunks of 160 = 1440
  const int tid = threadIdx.x;
  const int ffs = tid >> 3, g4s = (tid & 7) * 4;
  const int hb = tid & 7, hg = tid >> 3;
  const int fsub = (tid & 7) * 4, msub = (tid >> 3) * 4;

  uint2 pa; float pyv[8];
  auto loadRegs = [&](int gb) {
    const int f = f0 + ffs;
    pa = make_uint2(0u, 0u);
    if (f < F) pa = *(const uint2*)&Ab[(size_t)f * AbS + gb + g4s];
    const int gl = min(gb + hg, F - 1);   // pad cols of A are 0
#pragma unroll
    for (int r = 0; r < 8; ++r) pyv[r] = y1[(hb + 8 * r) * F + gl];
  };
  auto storeLDS = [&]() {
    Al[(g4s + 0) * 36 + ffs] = __uint_as_float(pa.x << 16);
    Al[(g4s + 1) * 36 + ffs] = __uint_as_float(pa.x & 0xffff0000u);
    Al[(g4s + 2) * 36 + ffs] = __uint_as_float(pa.y << 16);
    Al[(g4s + 3) * 36 + ffs] = __uint_as_float(pa.y & 0xffff0000u);
#pragma unroll
    for (int r = 0; r < 8; ++r) {
      const int bb = hb + 8 * r;
      const float v = pyv[r];
      float h0 = fmaf(k0, v, c0); h0 = h0 / (1.f + fabsf(h0));
      float h1 = fmaf(k1, v, c1); h1 = h1 / (1.f + fabsf(h1));
      *(float2*)&Hl[hg * 132 + 2 * bb] = make_float2(h0, h1);
    }
  };

  float acc[4][4] = {};
  loadRegs(gs);
  for (int c = 0; c < 5; ++c) {
    if (c) __syncthreads();           // previous compute done -> LDS reusable
    storeLDS();
    __syncthreads();
    if (c < 4) loadRegs(gs + (c + 1) * 32);   // next chunk in flight
#pragma unroll 4
    for (int gi = 0; gi < 32; ++gi) {
      float4 a4 = *(const float4*)&Al[gi * 36 + fsub];
      float4 h4 = *(const float4*)&Hl[gi * 132 + msub];
      float av[4] = {a4.x, a4.y, a4.z, a4.w};
      float hv[4] = {h4.x, h4.y, h4.z, h4.w};
#pragma unroll
      for (int i = 0; i < 4; ++i)
#pragma unroll
        for (int j = 0; j < 4; ++j)
          acc[i][j] = fmaf(av[i], hv[j], acc[i][j]);
    }
  }
  float* dst = G2P + (size_t)blockIdx.y * 128 * F;
#pragma unroll
  for (int i = 0; i < 4; ++i) {
    int f = f0 + fsub + i;
    if (f < F) {
#pragma unroll
      for (int j = 0; j < 4; ++j)
        dst[(msub + j) * F + f] = acc[i][j];
    }
  }
}

// ---------------- K5: reduce partials + 64*H diag -> y2, moments ----------
__global__ __launch_bounds__(256) void k_stats2(const float* __restrict__ y1,
                                                const float* __restrict__ G2P,
                                                const float* __restrict__ st,
                                                const float* __restrict__ W1,
                                                const float* __restrict__ g1,
                                                const float* __restrict__ be1,
                                                float* __restrict__ y2,
                                                float* __restrict__ stw) {
  const float mu = st[0] / (float)BF;
  const float var = st[1] / (float)BF - mu * mu;
  const float wa = W1[0], wb = W1[1];
  const float k0 = wa * g1[0] / sqrtf(wa * wa * var + EPS);
  const float k1 = wb * g1[1] / sqrtf(wb * wb * var + EPS);
  const float c0 = -k0 * mu + be1[0];
  const float c1 = -k1 * mu + be1[1];

  float su = 0.f, sv = 0.f, suu = 0.f, svv = 0.f, suv = 0.f;
  for (int i = blockIdx.x * 256 + threadIdx.x; i < BF; i += gridDim.x * 256) {
    int b = i / F, f = i - b * F;
    float w = y1[i];
    float h0 = fmaf(k0, w, c0); h0 = h0 / (1.f + fabsf(h0));
    float h1 = fmaf(k1, w, c1); h1 = h1 / (1.f + fabsf(h1));
    int iu = (2 * b) * F + f, iv = iu + F;
    float u = 64.f * h0, v = 64.f * h1;
#pragma unroll
    for (int t = 0; t < SK; ++t) {
      u += G2P[(size_t)t * 128 * F + iu];
      v += G2P[(size_t)t * 128 * F + iv];
    }
    y2[iu] = u; y2[iv] = v;
    su += u; sv += v; suu += u * u; svv += v * v; suv += u * v;
  }
#pragma unroll
  for (int o = 32; o; o >>= 1) {
    su += __shfl_down(su, o, 64);
    sv += __shfl_down(sv, o, 64);
    suu += __shfl_down(suu, o, 64);
    svv += __shfl_down(svv, o, 64);
    suv += __shfl_down(suv, o, 64);
  }
  __shared__ float red[5][4];
  int wave = threadIdx.x >> 6, lane = threadIdx.x & 63;
  if (lane == 0) {
    red[0][wave] = su; red[1][wave] = sv; red[2][wave] = suu;
    red[3][wave] = svv; red[4][wave] = suv;
  }
  __syncthreads();
  if (threadIdx.x == 0) {
#pragma unroll
    for (int m = 0; m < 5; ++m)
      atomicAdd(&stw[2 + m], red[m][0] + red[m][1] + red[m][2] + red[m][3]);
  }
}

// ---------------- K6: final classifier (BN2 consts inline) ----------------
__global__ __launch_bounds__(256) void k_out(const float* __restrict__ y2,
                                             const float* __restrict__ st,
                                             const float* __restrict__ W2,
                                             const float* __restrict__ b2,
                                             const float* __restrict__ g2,
                                             const float* __restrict__ be2,
                                             const float* __restrict__ Wc,
                                             const float* __restrict__ bc,
                                             float* __restrict__ out) {
  float n = (float)BF;
  float Eu = st[2] / n, Ev = st[3] / n;
  float Euu = st[4] / n, Evv = st[5] / n, Euv = st[6] / n;
  float cA[2], cB[2], cC[2];
#pragma unroll
  for (int o = 0; o < 2; ++o) {
    float w0 = W2[o * 2 + 0], w1 = W2[o * 2 + 1];
    float mean = w0 * Eu + w1 * Ev + b2[o];
    float Eh2 = w0 * w0 * Euu + 2.f * w0 * w1 * Euv + w1 * w1 * Evv +
                2.f * b2[o] * (w0 * Eu + w1 * Ev) + b2[o] * b2[o];
    float vr = Eh2 - mean * mean;
    float inv = g2[o] / sqrtf(vr + EPS);
    cA[o] = w0 * inv;
    cB[o] = w1 * inv;
    cC[o] = (b2[o] - mean) * inv + be2[o];
  }
  const int b = blockIdx.x;
  float acc[7] = {};
  for (int f = threadIdx.x; f < F; f += 256) {
    float u = y2[(2 * b) * F + f], v = y2[(2 * b + 1) * F + f];
    float h0 = fmaf(cA[0], u, fmaf(cB[0], v, cC[0]));
    h0 = h0 / (1.f + fabsf(h0));
    float h1 = fmaf(cA[1], u, fmaf(cB[1], v, cC[1]));
    h1 = h1 / (1.f + fabsf(h1));
#pragma unroll
    for (int o = 0; o < 7; ++o) acc[o] = fmaf(Wc[o * (2 * F) + f], h0, acc[o]);
#pragma unroll
    for (int o = 0; o < 7; ++o) acc[o] = fmaf(Wc[o * (2 * F) + F + f], h1, acc[o]);
  }
#pragma unroll
  for (int o = 0; o < 7; ++o) {
#pragma unroll
    for (int s = 32; s; s >>= 1) acc[o] += __shfl_down(acc[o], s, 64);
  }
  __shared__ float red[7][4];
  int wave = threadIdx.x >> 6, lane = threadIdx.x & 63;
  if (lane == 0) {
#pragma unroll
    for (int o = 0; o < 7; ++o) red[o][wave] = acc[o];
  }
  __syncthreads();
  if (threadIdx.x < 7) {
    int o = threadIdx.x;
    out[b * 7 + o] = red[o][0] + red[o][1] + red[o][2] + red[o][3] + bc[o];
  }
}

extern "C" void kernel_launch(void* const* d_in, const int* in_sizes, int n_in,
                              void* d_out, int out_size, void* d_ws, size_t ws_size,
                              hipStream_t stream) {
  const float* x    = (const float*)d_in[0];
  const float* nbr  = (const float*)d_in[1];
  const float* W1   = (const float*)d_in[3];
  const float* W2   = (const float*)d_in[5];
  const float* b2   = (const float*)d_in[6];
  const float* g1   = (const float*)d_in[7];
  const float* be1  = (const float*)d_in[8];
  const float* g2   = (const float*)d_in[9];
  const float* be2  = (const float*)d_in[10];
  const float* Wc   = (const float*)d_in[11];
  const float* bc   = (const float*)d_in[12];
  float* out = (float*)d_out;
  float* ws  = (float*)d_ws;

  float*  ys  = ws + O_YS;
  float*  DP  = ws + O_DP;
  float*  Y1P = ws + O_Y1P;
  float4* P   = (float4*)(ws + O_P);
  float*  y1  = ws + O_Y1;
  float*  y2  = ws + O_Y2;
  float*  G2P = ws + O_G2P;
  __hip_bfloat16* Ab = (__hip_bfloat16*)(ws + O_AB);
  float*  st  = ws + O_ST;

  k_ys    <<<dim3(NB, 6), 256, 0, stream>>>(nbr, ys, st);
  k_D     <<<dim3(NB, SF), 256, 0, stream>>>(x, ys, DP);
  k_y1    <<<dim3(NB, SF), 256, 0, stream>>>(x, ys, DP, Y1P, P);
  k_Astats<<<NA + NST, 256, 0, stream>>>(x, ys, P, Y1P, Ab, y1, st);
  k_gemm  <<<dim3(45, SK), 256, 0, stream>>>((const ushort*)Ab, y1, st, W1, g1, be1, G2P);
  k_stats2<<<NST, 256, 0, stream>>>(y1, G2P, st, W1, g1, be1, y2, st);
  k_out   <<<NB, 256, 0, stream>>>(y2, st, W2, b2, g2, be2, Wc, bc, out);
}